// Round 7
// baseline (1289.584 us; speedup 1.0000x reference)
//
#include <hip/hip_runtime.h>
#include <math.h>

#define HID    2048
#define NH     16
#define HD     128
#define SEQ    2048
#define NBATCH 2
#define NT     (SEQ / 64)

typedef __attribute__((ext_vector_type(8))) short bf16x8;   // 8 bf16 = 4 VGPRs
typedef __attribute__((ext_vector_type(4))) float f32x4;    // MFMA accumulator

__device__ __forceinline__ short f2bf(float f) {            // fp32 -> bf16 RNE
    union { float f; unsigned u; } x; x.f = f;
    unsigned r = x.u + 0x7fffu + ((x.u >> 16) & 1u);
    return (short)(r >> 16);
}
__device__ __forceinline__ float bf2f(short s) {
    union { unsigned u; float f; } y;
    y.u = ((unsigned)(unsigned short)s) << 16;
    return y.f;
}

// async global->LDS, 16 B per lane; LDS dest = wave-uniform base + lane*16
__device__ __forceinline__ void gl_lds16(const short* g, short* l) {
    __builtin_amdgcn_global_load_lds(
        (const __attribute__((address_space(1))) unsigned int*)g,
        (__attribute__((address_space(3))) unsigned int*)l, 16, 0, 0);
}

// ---------------------------------------------------------------------------
// Fused prep kernel: RoPE table + 3x fp32->bf16 casts in ONE launch.
// ---------------------------------------------------------------------------
#define ROPE_N  (SEQ * 64)                       // 131072
#define HS_N4   (NBATCH * SEQ * HID / 4)         // 2097152
#define WQKV_N4 (3 * HID * HID / 4)              // 3145728
#define WOUT_N4 (HID * HID / 4)                  // 1048576

__global__ __launch_bounds__(256) void prep_kernel(
    const float* __restrict__ hs, const float* __restrict__ Wqkv,
    const float* __restrict__ Wout,
    float2* __restrict__ cst, short* __restrict__ Ahs,
    short* __restrict__ Wqkvh, short* __restrict__ Wouth) {
    const long total = (long)ROPE_N + HS_N4 + WQKV_N4 + WOUT_N4;
    for (long idx = (long)blockIdx.x * 256 + threadIdx.x; idx < total;
         idx += (long)gridDim.x * 256) {
        if (idx < ROPE_N) {
            int s = (int)(idx >> 6);
            int i = (int)(idx & 63);
            double inv = pow(10000.0, -(double)i / 64.0);
            float freq = (float)s * (float)inv;
            float2 cs = make_float2(cosf(freq), sinf(freq));
            cst[s * HD + 2 * i]     = cs;
            cst[s * HD + 2 * i + 1] = cs;
        } else if (idx < (long)ROPE_N + HS_N4) {
            long i = idx - ROPE_N;
            float4 v = ((const float4*)hs)[i];
            short4 h;
            h.x = f2bf(v.x); h.y = f2bf(v.y); h.z = f2bf(v.z); h.w = f2bf(v.w);
            *(short4*)(Ahs + 4 * i) = h;
        } else if (idx < (long)ROPE_N + HS_N4 + WQKV_N4) {
            long i = idx - ROPE_N - HS_N4;
            float4 v = ((const float4*)Wqkv)[i];
            short4 h;
            h.x = f2bf(v.x); h.y = f2bf(v.y); h.z = f2bf(v.z); h.w = f2bf(v.w);
            *(short4*)(Wqkvh + 4 * i) = h;
        } else {
            long i = idx - ROPE_N - HS_N4 - WQKV_N4;
            float4 v = ((const float4*)Wout)[i];
            short4 h;
            h.x = f2bf(v.x); h.y = f2bf(v.y); h.z = f2bf(v.z); h.w = f2bf(v.w);
            *(short4*)(Wouth + 4 * i) = h;
        }
    }
}

// ---------------------------------------------------------------------------
// out-proj GEMM (m97 structure, unchanged): C = A.B^T + bias, fp32 out.
// ---------------------------------------------------------------------------
#define LDSA 0
#define LDSB 4096

__global__ __launch_bounds__(256, 3) void gemm_out_kernel(
    const short* __restrict__ Ah, const short* __restrict__ Bh,
    const float* __restrict__ bias, float* __restrict__ C) {
    __shared__ short lds[8192];

    const int t     = threadIdx.x;
    const int w     = t >> 6;
    const int lane  = t & 63;
    const int mfrag = lane & 15;
    const int quad  = lane >> 4;
    const int wm    = (w >> 1) * 64;
    const int wn    = (w & 1) * 64;
    const int m0    = blockIdx.y * 128;
    const int n0    = blockIdx.x * 128;

    const int srow   = lane >> 2;
    const int schunk = (((lane & 3) ^ ((lane >> 3) & 3))) * 8;
    const short* gA0 = Ah + (size_t)(m0 + w * 16 + srow) * HID + schunk;
    const short* gA1 = Ah + (size_t)(m0 + 64 + w * 16 + srow) * HID + schunk;
    const short* gB0 = Bh + (size_t)(n0 + w * 16 + srow) * HID + schunk;
    const short* gB1 = Bh + (size_t)(n0 + 64 + w * 16 + srow) * HID + schunk;
    short* lA0 = &lds[LDSA + (w * 16) * 32];
    short* lA1 = &lds[LDSA + (64 + w * 16) * 32];
    short* lB0 = &lds[LDSB + (w * 16) * 32];
    short* lB1 = &lds[LDSB + (64 + w * 16) * 32];

    const int chA = 8 * (quad ^ ((mfrag >> 1) & 3));  // inverse swizzle

    f32x4 acc[4][4];
#pragma unroll
    for (int i = 0; i < 4; ++i)
#pragma unroll
        for (int j = 0; j < 4; ++j) acc[i][j] = (f32x4){0.f, 0.f, 0.f, 0.f};

    for (int kt = 0; kt < HID; kt += 32) {
        __syncthreads();
        gl_lds16(gA0 + kt, lA0);
        gl_lds16(gA1 + kt, lA1);
        gl_lds16(gB0 + kt, lB0);
        gl_lds16(gB1 + kt, lB1);
        __syncthreads();

        bf16x8 ah[4], bh[4];
#pragma unroll
        for (int mt = 0; mt < 4; ++mt)
            ah[mt] = *(const bf16x8*)&lds[LDSA + (wm + mt * 16 + mfrag) * 32 + chA];
#pragma unroll
        for (int nt = 0; nt < 4; ++nt)
            bh[nt] = *(const bf16x8*)&lds[LDSB + (wn + nt * 16 + mfrag) * 32 + chA];

#pragma unroll
        for (int mt = 0; mt < 4; ++mt)
#pragma unroll
            for (int nt = 0; nt < 4; ++nt)
                acc[mt][nt] = __builtin_amdgcn_mfma_f32_16x16x32_bf16(
                    ah[mt], bh[nt], acc[mt][nt], 0, 0, 0);
    }

    float bcol[4];
#pragma unroll
    for (int nt = 0; nt < 4; ++nt) bcol[nt] = bias[n0 + wn + nt * 16 + mfrag];

#pragma unroll
    for (int mt = 0; mt < 4; ++mt)
#pragma unroll
        for (int r = 0; r < 4; ++r) {
            int mm = m0 + wm + mt * 16 + 4 * quad + r;
#pragma unroll
            for (int nt = 0; nt < 4; ++nt)
                C[(size_t)mm * HID + n0 + wn + nt * 16 + mfrag] =
                    acc[mt][nt][r] + bcol[nt];
        }
}

// ---------------------------------------------------------------------------
// QKV GEMM: 256x256 tile, BK=32, 8-phase, LDS 64 KB -> 2 BLOCKS/CU.
// All 384 blocks co-resident (no dispatch tail); the two blocks per CU have
// independent barriers so one block's MFMA fills the other's drain stalls.
// Per iter = 2 K-tiles of 32. Buffers: buf k at k*16384 shorts {A 8192 | B
// 8192}. Row = 32 shorts = 4 chunks of 16B; XOR key = row&3 (stage source
// pre-swizzled, read side inverse -- same involution).
// Stages front-loaded: P1/P2 stage buf1 (tile 2i+1, consumed P5-P8);
// P5/P6 stage buf0 (tile 2i+2, consumed next P1-P4). vmcnt(0) at P4 and P8
// only (2 drains per 8 phases; co-resident partner block hides them).
// Epilogue identical to round 5 except V-transpose runs in two wave-halves
// (64 KB LDS), serialized by block-uniform barriers.
// ---------------------------------------------------------------------------
#define PR1 __builtin_amdgcn_s_setprio(1)
#define PR0 __builtin_amdgcn_s_setprio(0)
#define BARX __builtin_amdgcn_s_barrier()
#define LGKM0 asm volatile("s_waitcnt lgkmcnt(0)" ::: "memory")
#define VMC(n) asm volatile("s_waitcnt vmcnt(" #n ")" ::: "memory")

// one K-tile (256 rows x 32 k): 2 gl_lds per operand; call c covers rows
// c*128..c*128+127 (each wave stages 16 rows / 512 shorts per call)
#define STAGE_A32(bf, ke, c) \
    gl_lds16(Ag + (size_t)((c) * 128) * HID + (ke), \
             &lds[(bf) * 16384 + sdst + (c) * 4096]);
#define STAGE_B32(bf, ke, c) \
    gl_lds16(Bg + (size_t)((c) * 128) * HID + (ke), \
             &lds[(bf) * 16384 + 8192 + sdst + (c) * 4096]);

#define LOADA(bf, mh) { _Pragma("unroll") for (int x = 0; x < 4; ++x) \
    aF[x] = *(const bf16x8*)&lds[(bf) * 16384 + aoff + ((mh) * 4 + x) * 512 + fcA]; }
#define LOADB(bf, nh, dstF) { _Pragma("unroll") for (int y = 0; y < 2; ++y) \
    dstF[y] = *(const bf16x8*)&lds[(bf) * 16384 + 8192 + boff + ((nh) * 2 + y) * 512 + fcA]; }
#define QUADM(mh, nh, bF) { _Pragma("unroll") for (int x = 0; x < 4; ++x) \
    _Pragma("unroll") for (int y = 0; y < 2; ++y) \
    acc[(mh) * 4 + x][(nh) * 2 + y] = __builtin_amdgcn_mfma_f32_16x16x32_bf16( \
        aF[x], bF[y], acc[(mh) * 4 + x][(nh) * 2 + y], 0, 0, 0); }

__global__ __launch_bounds__(512, 4) void gemm256_qkv_kernel(
    const short* __restrict__ Ah, const short* __restrict__ Bh,
    const float* __restrict__ bias,
    short* __restrict__ qb, short* __restrict__ kbf, short* __restrict__ vTt,
    const float2* __restrict__ cst) {
    __shared__ __align__(16) short lds[32768];   // 64 KB -> 2 blocks/CU

    const int t    = threadIdx.x;
    const int w    = t >> 6;            // 0..7
    const int lane = t & 63;
    const int m    = lane & 15;
    const int quad = lane >> 4;
    const int wm   = w >> 2;            // 0..1  (M half)
    const int wn   = w & 3;             // 0..3  (N quarter)

    // XCD-aware bijective swizzle: nwg=384, 384%8==0
    const int swz = (blockIdx.x & 7) * 48 + (blockIdx.x >> 3);
    const int bx  = swz / 16;           // 0..23 -> N
    const int by  = swz % 16;           // 0..15 -> M
    const int m0  = by * 256;
    const int n0  = bx * 256;

    // staging: per-lane pre-swizzled global base (chunk ^= row&3)
    const int srl = lane >> 2;                       // row in 16-row wave stripe
    const int sch = ((lane & 3) ^ (srl & 3)) * 8;    // swizzled 16B chunk
    const short* Ag = Ah + (size_t)(m0 + w * 16 + srl) * HID + sch;
    const short* Bg = Bh + (size_t)(n0 + w * 16 + srl) * HID + sch;
    const int sdst  = w * 512;          // wave's 16-row stripe (shorts)

    // fragment-read constants (inverse chunk swizzle, key = row&3 = m&3)
    const int fcA  = (quad ^ (m & 3)) * 8;
    const int aoff = (wm * 128 + m) * 32;
    const int boff = (wn * 64 + m) * 32;

    f32x4 acc[8][4];
#pragma unroll
    for (int i = 0; i < 8; ++i)
#pragma unroll
        for (int j = 0; j < 4; ++j) acc[i][j] = (f32x4){0.f, 0.f, 0.f, 0.f};

    bf16x8 aF[4], b0F[2], b1F[2];

    // prologue: stage buf0 (tile 0), full drain
    STAGE_A32(0, 0, 0); STAGE_A32(0, 0, 1);
    STAGE_B32(0, 0, 0); STAGE_B32(0, 0, 1);
    VMC(0); BARX;

    const int NIT = HID / 64;           // 32 iterations, 2 K-tiles of 32 each
#pragma unroll 1
    for (int i = 0; i < NIT; ++i) {
        const int k1   = i * 64 + 32;       // tile 2i+1 (buf1)
        const int k2   = (i + 1) * 64;      // tile 2i+2 (buf0)
        const bool more = (i + 1 < NIT);
        // ======== K-tile 2i (buf0) ========
        // P1: ds A-mh0 + B-nh0; stage buf1-A (both chunks)
        LOADA(0, 0); LOADB(0, 0, b0F);
        STAGE_A32(1, k1, 0); STAGE_A32(1, k1, 1);
        BARX; LGKM0; PR1; QUADM(0, 0, b0F); PR0; BARX;
        // P2: ds B-nh1; stage buf1-B (both chunks)
        LOADB(0, 1, b1F);
        STAGE_B32(1, k1, 0); STAGE_B32(1, k1, 1);
        BARX; LGKM0; PR1; QUADM(0, 1, b1F); PR0; BARX;
        // P3: ds A-mh1
        LOADA(0, 1);
        BARX; LGKM0; PR1; QUADM(1, 1, b1F); PR0; BARX;
        // P4: drain -> buf1 complete before P5 reads (barrier publishes)
        VMC(0);
        BARX; PR1; QUADM(1, 0, b0F); PR0; BARX;
        // ======== K-tile 2i+1 (buf1) ========
        // P5: ds A-mh0 + B-nh0; stage buf0-A of tile 2i+2
        LOADA(1, 0); LOADB(1, 0, b0F);
        if (more) { STAGE_A32(0, k2, 0); STAGE_A32(0, k2, 1); }
        BARX; LGKM0; PR1; QUADM(0, 0, b0F); PR0; BARX;
        // P6: ds B-nh1; stage buf0-B of tile 2i+2
        LOADB(1, 1, b1F);
        if (more) { STAGE_B32(0, k2, 0); STAGE_B32(0, k2, 1); }
        BARX; LGKM0; PR1; QUADM(0, 1, b1F); PR0; BARX;
        // P7: ds A-mh1
        LOADA(1, 1);
        BARX; LGKM0; PR1; QUADM(1, 1, b1F); PR0; BARX;
        // P8: drain -> buf0 complete before next P1 reads
        VMC(0);
        BARX; PR1; QUADM(1, 0, b0F); PR0; BARX;
    }

    // -------- epilogue --------
    const int which = n0 >> 11;          // 0=q 1=k 2=v
    const int bidx  = m0 >> 11;
    const int cb    = (n0 & 2047) + wn * 64;
    const int h     = cb >> 7;
    const int d0    = cb & 127;

    float bcol[4];
#pragma unroll
    for (int nt = 0; nt < 4; ++nt) bcol[nt] = bias[n0 + wn * 64 + nt * 16 + m];

    if (which < 2) {
        short* dst = (which == 0) ? qb : kbf;
        const float post = (which == 0) ? 0.08838834764831845f : 1.0f;
#pragma unroll
        for (int mt = 0; mt < 8; ++mt)
#pragma unroll
            for (int r = 0; r < 4; ++r) {
                int sl = (m0 & 2047) + wm * 128 + mt * 16 + 4 * quad + r;
                const float2* csr = cst + (size_t)sl * HD;
                size_t rowb = ((size_t)(bidx * NH + h) * SEQ + sl) * HD;
#pragma unroll
                for (int nt = 0; nt < 4; ++nt) {
                    float x  = acc[mt][nt][r] + bcol[nt];
                    float px = __shfl_xor(x, 1, 64);   // RoPE pair partner
                    int   d  = d0 + nt * 16 + m;
                    float2 cs = csr[d];
                    float rot = (m & 1) ? fmaf(px, cs.y, x * cs.x)
                                        : (x * cs.x - px * cs.y);
                    dst[rowb + d] = f2bf(rot * post);
                }
            }
    } else {
        // V: per-wave transpose via (dead) staging LDS -> vT [b][h][d][s].
        // 64 KB LDS only fits 4 wave-buffers -> run in two wave-halves,
        // serialized by block-uniform barriers.
        short* tw = &lds[(w & 3) * 8192];   // 64 d-rows x 128 s, chunk ^= d&15
        const size_t vbase = (size_t)(bidx * NH + h) * HD * SEQ;
        const int sbase = (m0 & 2047) + wm * 128;
#pragma unroll
        for (int half = 0; half < 2; ++half) {
            if ((w >> 2) == half) {
#pragma unroll
                for (int mt = 0; mt < 8; ++mt)
#pragma unroll
                    for (int nt = 0; nt < 4; ++nt)
#pragma unroll
                        for (int r = 0; r < 4; ++r) {
                            int s_l = mt * 16 + 4 * quad + r;
                            int d_l = nt * 16 + m;
                            tw[d_l * 128 + (((s_l >> 3) ^ m) << 3) + (s_l & 7)] =
                                f2bf(acc[mt][nt][r] + bcol[nt]);
                        }
#pragma unroll
                for (int it = 0; it < 16; ++it) {
                    int d_l = it * 4 + quad;
                    bf16x8 row = *(const bf16x8*)&tw[d_l * 128 +
                                                    ((m ^ (d_l & 15)) << 3)];
                    *(bf16x8*)(vTt + vbase + (size_t)(d0 + d_l) * SEQ +
                               sbase + m * 8) = row;
                }
            }
            __syncthreads();
        }
    }
}

// ---------------------------------------------------------------------------
// MFMA flash attention (unchanged, passing since round 1): 8 waves, q-tile
// 128, KV tile 64 double-buffered, defer-max softmax, cvt_pk, setprio.
// ---------------------------------------------------------------------------
#define AK0 0
#define AK1 8192
#define AV0 16384
#define AV1 24576
#define AP  32768

__global__ __launch_bounds__(512, 4) void attn_mfma_kernel(
    const short* __restrict__ qb, const short* __restrict__ kbf,
    const short* __restrict__ vTt, const float* __restrict__ mask,
    short* __restrict__ ctxb) {
    __shared__ __align__(16) short lds[40960];   // 80 KB

    const int t    = threadIdx.x;
    const int w    = t >> 6;            // 0..7
    const int lane = t & 63;
    const int m    = lane & 15;
    const int quad = lane >> 4;

    const int id  = blockIdx.x;
    const int j   = id >> 3;
    const int bh  = (id & 7) * 4 + (j >> 4);
    const int q0  = (j & 15) * 128;
    const int b   = bh >> 4;
    const int h   = bh & 15;

    const size_t base = (size_t)bh * SEQ * HD;
    const short* kp = kbf + base;        // [s][d]
    const short* vp = vTt + base;        // [d][s]
    const float* mrow = mask + (size_t)b * SEQ;

    size_t kOff[2], vOff[2];
    int kDst[2], vDst[2];
#pragma unroll
    for (int u = 0; u < 2; ++u) {
        int rk = w * 8 + u * 4 + (lane >> 4);
        int ck = (lane & 15) ^ (rk & 7);
        kOff[u] = (size_t)rk * HD + ck * 8;
        kDst[u] = (w * 8 + u * 4) * 128;
        int rv = w * 16 + u * 8 + (lane >> 3);
        int cv = (lane & 7) ^ (rv & 7);
        vOff[u] = (size_t)rv * SEQ + cv * 8;
        vDst[u] = (w * 16 + u * 8) * 64;
    }

    const int srow = q0 + w * 16 + m;
    bf16x8 qh[4];
    {
        const short* qhp = qb + base + (size_t)srow * HD;
#pragma unroll
        for (int c = 0; c < 4; ++c)
            qh[c] = *(const bf16x8*)(qhp + 32 * c + 8 * quad);
    }

    f32x4 O[8];
    float m_i[4], l_p[4];
#pragma unroll
    for (int c = 0; c < 8; ++c) O[c] = (f32x4){0.f, 0.f, 0.f, 0.f};
#pragma unroll
    for (int r = 0; r < 4; ++r) { m_i[r] = -INFINITY; l_p[r] = 0.f; }

    const int sw = m & 7;
    const int pb = AP + w * 1024;
    const int kcb = (m >> 3);
    const int ml  = m & 7;

#pragma unroll
    for (int u = 0; u < 2; ++u) {
        gl_lds16(kp + kOff[u], &lds[AK0 + kDst[u]]);
        gl_lds16(vp + vOff[u], &lds[AV0 + vDst[u]]);
    }

    for (int kt = 0; kt < NT; ++kt) {
        const int cur = kt & 1;
        const int k0  = kt * 64;

        __syncthreads();

        if (kt + 1 < NT) {
            const int nk0 = (kt + 1) * 64;
            const int nb  = cur ^ 1;
#pragma unroll
            for (int u = 0; u < 2; ++u) {
                gl_lds16(kp + (size_t)nk0 * HD + kOff[u],
                         &lds[(nb ? AK1 : AK0) + kDst[u]]);
                gl_lds16(vp + nk0 + vOff[u],
                         &lds[(nb ? AV1 : AV0) + vDst[u]]);
            }
        }

        const short* kb = &lds[cur ? AK1 : AK0];
        const short* vb = &lds[cur ? AV1 : AV0];

        float mk[4];
#pragma unroll
        for (int c2 = 0; c2 < 4; ++c2) mk[c2] = mrow[k0 + 16 * c2 + m];

        f32x4 S[4];
        __builtin_amdgcn_s_setprio(1);
#pragma unroll
        for (int c2 = 0; c2 < 4; ++c2) {
            f32x4 acc = (f32x4){0.f, 0.f, 0.f, 0.f};
#pragma unroll
            for (int c = 0; c < 4; ++c) {
                int pk = (4 * c + quad) ^ sw;
                bf16x8 kf = *(const bf16x8*)&kb[(16 * c2 + m) * 128 + pk * 8];
                acc = __builtin_amdgcn_mfma_f32_16x16x32_bf16(qh[c], kf, acc, 0, 0, 0);
            }
            S[c2] = acc;
        }
        __builtin_amdgcn_s_setprio(0);

        float rm4[4];
#pragma unroll
        for (int r = 0; r < 4; ++r) {
            float s0 = S[0][r] + mk[0];
            float s1 = S[1][r] + mk[1];
            float s2 = S[2][r] + mk[2];
            float s3 = S[3][r] + mk[3];
            S[0][r] = s0; S[1][r] = s1; S[2][r] = s2; S[3][r] = s3;
            float rm = fmaxf(fmaxf(s0, s1), fmaxf(s2, s3));
#pragma unroll
            for (int off = 1; off < 16; off <<= 1)
                rm = fmaxf(rm, __shfl_xor(rm, off, 64));
            rm4[r] = rm;
        }
        int needI = (rm4[0] > m_i[0] + 8.f) | (rm4[1] > m_i[1] + 8.f) |
                    (rm4[2] > m_i[2] + 8.f) | (rm4[3] > m_i[3] + 8.f);
        if (__any(needI)) {
#pragma unroll
            for (int r = 0; r < 4; ++r) {
                float mn = fmaxf(m_i[r], rm4[r]);
                float a  = __expf(m_i[r] - mn);
                m_i[r]   = mn;
                l_p[r]  *= a;
#pragma unroll
                for (int c = 0; c < 8; ++c) O[c][r] *= a;
            }
        }
        float p[4][4];
#pragma unroll
        for (int r = 0; r < 4; ++r) {
#pragma unroll
            for (int c2 = 0; c2 < 4; ++c2) p[c2][r] = __expf(S[c2][r] - m_i[r]);
            l_p[r] += (p[0][r] + p[1][r]) + (p[2][r] + p[3][r]);
        }

#pragma unroll
        for (int c2 = 0; c2 < 4; ++c2) {
#pragma unroll
            for (int jj = 0; jj < 2; ++jj) {
                unsigned pkw;
                asm("v_cvt_pk_bf16_f32 %0, %1, %2"
                    : "=v"(pkw) : "v"(p[c2][2 * jj]), "v"(p[c2][2 * jj + 1]));
                int ql = 4 * quad + 2 * jj;
                int qh2 = ql + 1;
                lds[pb + ql * 64 + (((2 * c2 + kcb) ^ (ql & 7)) << 3) + ml] =
                    (short)(pkw & 0xffffu);
                lds[pb + qh2 * 64 + (((2 * c2 + kcb) ^ (qh2 & 7)) << 3) + ml] =
                    (short)(pkw >> 16);
            }
        }

        __builtin_amdgcn_s_setprio(1);
#pragma unroll
        for (int cc = 0; cc < 2; ++cc) {
            int pv = (4 * cc + quad) ^ sw;
            bf16x8 pf = *(const bf16x8*)&lds[pb + m * 64 + (pv << 3)];
#pragma unroll
            for (int c = 0; c < 8; ++c) {
                bf16x8 vf = *(const bf16x8*)&vb[(16 * c + m) * 64 + pv * 8];
                O[c] = __builtin_amdgcn_mfma_f32_16x16x32_bf16(pf, vf, O[c], 0, 0, 0);
            }
        }
        __builtin_amdgcn_s_setprio(0);
    }

#pragma unroll
    for (int r = 0; r < 4; ++r) {
        float lv = l_p[r];
#pragma unroll
        for (int off = 1; off < 16; off <<= 1) lv += __shfl_xor(lv, off, 64);
        float inv = 1.0f / lv;
        int s = q0 + w * 16 + 4 * quad + r;
        size_t off2 = ((size_t)(b * SEQ + s)) * HID + h * HD;
#pragma unroll
        for (int c = 0; c < 8; ++c)
            ctxb[off2 + 16 * c + m] = f2bf(O[c][r] * inv);
    }
}

// ---------------------------------------------------------------------------
extern "C" void kernel_launch(void* const* d_in, const int* in_sizes, int n_in,
                              void* d_out, int out_size, void* d_ws, size_t ws_size,
                              hipStream_t stream) {
    const float* hs   = (const float*)d_in[0];
    const float* mask = (const float*)d_in[1];
    const float* Wqkv = (const float*)d_in[2];
    const float* bqkv = (const float*)d_in[3];
    const float* Wout = (const float*)d_in[4];
    const float* bout = (const float*)d_in[5];
    float* out = (float*)d_out;

    const size_t qkv_elems = (size_t)NBATCH * NH * SEQ * HD;  // 8.39M
    char* p = (char*)d_ws;
    float2* cst  = (float2*)p; p += (size_t)SEQ * HD * 8;   // fused cos/sin, 2 MB
    short* qbf   = (short*)p; p += qkv_elems * 2;
    short* kbf   = (short*)p; p += qkv_elems * 2;
    short* vTt   = (short*)p; p += qkv_elems * 2;
    short* Wqkvh = (short*)p; p += (size_t)3 * HID * HID * 2;
    short* Wouth = (short*)p; p += (size_t)HID * HID * 2;
    short* Ahs   = (short*)p; p += qkv_elems * 2;   // bf16(hs); aliased ctx after QKV
    short* ctxb  = Ahs;

    // fused prep: RoPE table + bf16 casts of hs / Wqkv / Wout (1 launch)
    prep_kernel<<<2048, 256, 0, stream>>>(hs, Wqkv, Wout, cst, Ahs, Wqkvh, Wouth);

    // QKV: M=4096, N=6144, K=2048 -> 384 blocks of 512, BK=32, 2 blocks/CU
    gemm256_qkv_kernel<<<384, 512, 0, stream>>>(
        Ahs, Wqkvh, bqkv, qbf, kbf, vTt, cst);

    // attention: 512 XCD-swizzled blocks of 512 threads
    attn_mfma_kernel<<<512, 512, 0, stream>>>(qbf, kbf, vTt, mask, ctxb);

    // out-proj: M=4096, N=2048, K=2048 (m97 structure)
    gemm_out_kernel<<<dim3(16, 32), 256, 0, stream>>>(ctxb, Wouth, bout, out);
}

// Round 8
// 422.370 us; speedup vs baseline: 3.0532x; 3.0532x over previous
//
#include <hip/hip_runtime.h>
#include <math.h>

#define HID    2048
#define NH     16
#define HD     128
#define SEQ    2048
#define NBATCH 2
#define NT     (SEQ / 64)

typedef __attribute__((ext_vector_type(8))) short bf16x8;   // 8 bf16 = 4 VGPRs
typedef __attribute__((ext_vector_type(4))) float f32x4;    // MFMA accumulator

__device__ __forceinline__ short f2bf(float f) {            // fp32 -> bf16 RNE
    union { float f; unsigned u; } x; x.f = f;
    unsigned r = x.u + 0x7fffu + ((x.u >> 16) & 1u);
    return (short)(r >> 16);
}
__device__ __forceinline__ float bf2f(short s) {
    union { unsigned u; float f; } y;
    y.u = ((unsigned)(unsigned short)s) << 16;
    return y.f;
}

// async global->LDS, 16 B per lane; LDS dest = wave-uniform base + lane*16
__device__ __forceinline__ void gl_lds16(const short* g, short* l) {
    __builtin_amdgcn_global_load_lds(
        (const __attribute__((address_space(1))) unsigned int*)g,
        (__attribute__((address_space(3))) unsigned int*)l, 16, 0, 0);
}

// ---------------------------------------------------------------------------
// Fused prep kernel: RoPE table + 3x fp32->bf16 casts in ONE launch.
// ---------------------------------------------------------------------------
#define ROPE_N  (SEQ * 64)                       // 131072
#define HS_N4   (NBATCH * SEQ * HID / 4)         // 2097152
#define WQKV_N4 (3 * HID * HID / 4)              // 3145728
#define WOUT_N4 (HID * HID / 4)                  // 1048576

__global__ __launch_bounds__(256) void prep_kernel(
    const float* __restrict__ hs, const float* __restrict__ Wqkv,
    const float* __restrict__ Wout,
    float2* __restrict__ cst, short* __restrict__ Ahs,
    short* __restrict__ Wqkvh, short* __restrict__ Wouth) {
    const long total = (long)ROPE_N + HS_N4 + WQKV_N4 + WOUT_N4;
    for (long idx = (long)blockIdx.x * 256 + threadIdx.x; idx < total;
         idx += (long)gridDim.x * 256) {
        if (idx < ROPE_N) {
            int s = (int)(idx >> 6);
            int i = (int)(idx & 63);
            double inv = pow(10000.0, -(double)i / 64.0);
            float freq = (float)s * (float)inv;
            float2 cs = make_float2(cosf(freq), sinf(freq));
            cst[s * HD + 2 * i]     = cs;
            cst[s * HD + 2 * i + 1] = cs;
        } else if (idx < (long)ROPE_N + HS_N4) {
            long i = idx - ROPE_N;
            float4 v = ((const float4*)hs)[i];
            short4 h;
            h.x = f2bf(v.x); h.y = f2bf(v.y); h.z = f2bf(v.z); h.w = f2bf(v.w);
            *(short4*)(Ahs + 4 * i) = h;
        } else if (idx < (long)ROPE_N + HS_N4 + WQKV_N4) {
            long i = idx - ROPE_N - HS_N4;
            float4 v = ((const float4*)Wqkv)[i];
            short4 h;
            h.x = f2bf(v.x); h.y = f2bf(v.y); h.z = f2bf(v.z); h.w = f2bf(v.w);
            *(short4*)(Wqkvh + 4 * i) = h;
        } else {
            long i = idx - ROPE_N - HS_N4 - WQKV_N4;
            float4 v = ((const float4*)Wout)[i];
            short4 h;
            h.x = f2bf(v.x); h.y = f2bf(v.y); h.z = f2bf(v.z); h.w = f2bf(v.w);
            *(short4*)(Wouth + 4 * i) = h;
        }
    }
}

// ---------------------------------------------------------------------------
// out-proj GEMM (m97 structure, unchanged): C = A.B^T + bias, fp32 out.
// ---------------------------------------------------------------------------
#define LDSA 0
#define LDSB 4096

__global__ __launch_bounds__(256, 3) void gemm_out_kernel(
    const short* __restrict__ Ah, const short* __restrict__ Bh,
    const float* __restrict__ bias, float* __restrict__ C) {
    __shared__ short lds[8192];

    const int t     = threadIdx.x;
    const int w     = t >> 6;
    const int lane  = t & 63;
    const int mfrag = lane & 15;
    const int quad  = lane >> 4;
    const int wm    = (w >> 1) * 64;
    const int wn    = (w & 1) * 64;
    const int m0    = blockIdx.y * 128;
    const int n0    = blockIdx.x * 128;

    const int srow   = lane >> 2;
    const int schunk = (((lane & 3) ^ ((lane >> 3) & 3))) * 8;
    const short* gA0 = Ah + (size_t)(m0 + w * 16 + srow) * HID + schunk;
    const short* gA1 = Ah + (size_t)(m0 + 64 + w * 16 + srow) * HID + schunk;
    const short* gB0 = Bh + (size_t)(n0 + w * 16 + srow) * HID + schunk;
    const short* gB1 = Bh + (size_t)(n0 + 64 + w * 16 + srow) * HID + schunk;
    short* lA0 = &lds[LDSA + (w * 16) * 32];
    short* lA1 = &lds[LDSA + (64 + w * 16) * 32];
    short* lB0 = &lds[LDSB + (w * 16) * 32];
    short* lB1 = &lds[LDSB + (64 + w * 16) * 32];

    const int chA = 8 * (quad ^ ((mfrag >> 1) & 3));  // inverse swizzle

    f32x4 acc[4][4];
#pragma unroll
    for (int i = 0; i < 4; ++i)
#pragma unroll
        for (int j = 0; j < 4; ++j) acc[i][j] = (f32x4){0.f, 0.f, 0.f, 0.f};

    for (int kt = 0; kt < HID; kt += 32) {
        __syncthreads();
        gl_lds16(gA0 + kt, lA0);
        gl_lds16(gA1 + kt, lA1);
        gl_lds16(gB0 + kt, lB0);
        gl_lds16(gB1 + kt, lB1);
        __syncthreads();

        bf16x8 ah[4], bh[4];
#pragma unroll
        for (int mt = 0; mt < 4; ++mt)
            ah[mt] = *(const bf16x8*)&lds[LDSA + (wm + mt * 16 + mfrag) * 32 + chA];
#pragma unroll
        for (int nt = 0; nt < 4; ++nt)
            bh[nt] = *(const bf16x8*)&lds[LDSB + (wn + nt * 16 + mfrag) * 32 + chA];

#pragma unroll
        for (int mt = 0; mt < 4; ++mt)
#pragma unroll
            for (int nt = 0; nt < 4; ++nt)
                acc[mt][nt] = __builtin_amdgcn_mfma_f32_16x16x32_bf16(
                    ah[mt], bh[nt], acc[mt][nt], 0, 0, 0);
    }

    float bcol[4];
#pragma unroll
    for (int nt = 0; nt < 4; ++nt) bcol[nt] = bias[n0 + wn + nt * 16 + mfrag];

#pragma unroll
    for (int mt = 0; mt < 4; ++mt)
#pragma unroll
        for (int r = 0; r < 4; ++r) {
            int mm = m0 + wm + mt * 16 + 4 * quad + r;
#pragma unroll
            for (int nt = 0; nt < 4; ++nt)
                C[(size_t)mm * HID + n0 + wn + nt * 16 + mfrag] =
                    acc[mt][nt][r] + bcol[nt];
        }
}

// ---------------------------------------------------------------------------
// QKV GEMM: 256x256 tile, BK=64, 8-phase schedule (T2+T3+T4+T5 per m201).
// RESTORED round-5 version (verified 131.1 us, VGPR 128, MfmaUtil 33%).
// Round-7 lesson: launch_bounds(512,4) caps VGPR at 128 < acc[8][4] alone
// -> accumulator spills to scratch (FETCH 1.75 GB, MfmaUtil 4%). The 256^2
// tile is register-bound to 1 block/CU; do NOT raise the occupancy bound.
// ---------------------------------------------------------------------------
#define PR1 __builtin_amdgcn_s_setprio(1)
#define PR0 __builtin_amdgcn_s_setprio(0)
#define BARX __builtin_amdgcn_s_barrier()
#define LGKM0 asm volatile("s_waitcnt lgkmcnt(0)" ::: "memory")
#define VMC(n) asm volatile("s_waitcnt vmcnt(" #n ")" ::: "memory")

// half-tile stages: hh=0 -> rows 0..127 (chunks c=0,1), hh=1 -> rows 128..255
#define STAGE_AH(bf, ke, hh) { _Pragma("unroll") for (int c = 0; c < 2; ++c) \
    gl_lds16(Ag + (size_t)(((hh) * 2 + c) * 64) * HID + (ke), \
             &lds[(bf) * 32768 + sdst + ((hh) * 2 + c) * 4096]); }
#define STAGE_BH(bf, ke, hh) { _Pragma("unroll") for (int c = 0; c < 2; ++c) \
    gl_lds16(Bg + (size_t)(((hh) * 2 + c) * 64) * HID + (ke), \
             &lds[(bf) * 32768 + 16384 + sdst + ((hh) * 2 + c) * 4096]); }

#define LOADA(bf, mh) { _Pragma("unroll") for (int x = 0; x < 4; ++x) { \
    aF[x][0] = *(const bf16x8*)&lds[(bf) * 32768 + aoff + ((mh) * 4 + x) * 1024 + fc0]; \
    aF[x][1] = *(const bf16x8*)&lds[(bf) * 32768 + aoff + ((mh) * 4 + x) * 1024 + fc1]; } }
#define LOADB(bf, nh, dstF) { _Pragma("unroll") for (int x = 0; x < 2; ++x) { \
    dstF[x][0] = *(const bf16x8*)&lds[(bf) * 32768 + 16384 + boff + ((nh) * 2 + x) * 1024 + fc0]; \
    dstF[x][1] = *(const bf16x8*)&lds[(bf) * 32768 + 16384 + boff + ((nh) * 2 + x) * 1024 + fc1]; } }
#define QUADM(mh, nh, bF) { _Pragma("unroll") for (int x = 0; x < 4; ++x) \
    _Pragma("unroll") for (int y = 0; y < 2; ++y) { \
    acc[(mh) * 4 + x][(nh) * 2 + y] = __builtin_amdgcn_mfma_f32_16x16x32_bf16( \
        aF[x][0], bF[y][0], acc[(mh) * 4 + x][(nh) * 2 + y], 0, 0, 0); \
    acc[(mh) * 4 + x][(nh) * 2 + y] = __builtin_amdgcn_mfma_f32_16x16x32_bf16( \
        aF[x][1], bF[y][1], acc[(mh) * 4 + x][(nh) * 2 + y], 0, 0, 0); } }

__global__ __launch_bounds__(512, 2) void gemm256_qkv_kernel(
    const short* __restrict__ Ah, const short* __restrict__ Bh,
    const float* __restrict__ bias,
    short* __restrict__ qb, short* __restrict__ kbf, short* __restrict__ vTt,
    const float2* __restrict__ cst) {
    __shared__ __align__(16) short lds[65536];   // 128 KB

    const int t    = threadIdx.x;
    const int w    = t >> 6;            // 0..7
    const int lane = t & 63;
    const int m    = lane & 15;
    const int quad = lane >> 4;
    const int wm   = w >> 2;            // 0..1  (M half)
    const int wn   = w & 3;             // 0..3  (N quarter)

    // XCD-aware bijective swizzle: nwg=384, 384%8==0
    const int swz = (blockIdx.x & 7) * 48 + (blockIdx.x >> 3);
    const int bx  = swz / 16;           // 0..23 -> N
    const int by  = swz % 16;           // 0..15 -> M
    const int m0  = by * 256;
    const int n0  = bx * 256;

    // staging: per-lane pre-swizzled global base (chunk ^= row&7)
    const int srl = lane >> 3;
    const int sch = ((lane & 7) ^ (srl & 7)) * 8;
    const short* Ag = Ah + (size_t)(m0 + w * 8 + srl) * HID + sch;
    const short* Bg = Bh + (size_t)(n0 + w * 8 + srl) * HID + sch;
    const int sdst  = w * 512;          // wave's 8-row stripe (shorts)

    // fragment-read constants (inverse chunk swizzle, key = row&7 = m&7)
    const int key  = m & 7;
    const int fc0  = (quad ^ key) * 8;
    const int fc1  = ((4 + quad) ^ key) * 8;
    const int aoff = (wm * 128 + m) * 64;
    const int boff = (wn * 64 + m) * 64;

    f32x4 acc[8][4];
#pragma unroll
    for (int i = 0; i < 8; ++i)
#pragma unroll
        for (int j = 0; j < 4; ++j) acc[i][j] = (f32x4){0.f, 0.f, 0.f, 0.f};

    bf16x8 aF[4][2], b0F[2][2], b1F[2][2];

    // prologue: stage buf0 (tile 0: A+B, 8 loads) + buf1-B (tile 1, 4 loads)
    STAGE_AH(0, 0, 0); STAGE_AH(0, 0, 1);
    STAGE_BH(0, 0, 0); STAGE_BH(0, 0, 1);
    STAGE_BH(1, 64, 0); STAGE_BH(1, 64, 1);
    VMC(4); BARX;   // retires buf0's 8; buf1-B (4) stays in flight

    const int NIT = HID / 128;          // 16 iterations, 2 K-tiles each
#pragma unroll 1
    for (int i = 0; i < NIT; ++i) {
        const int k1   = i * 128 + 64;      // tile 2i+1 k-offset (buf1-A)
        const int k2   = (i + 1) * 128;     // tile 2i+2 (buf0)
        const int k3   = k2 + 64;           // tile 2i+3 (buf1-B)
        const bool more = (i + 1 < NIT);
        // ======== K-tile 2i (buf0) ========
        // P1: ds A-mh0 + B-nh0; stage buf1-A-h0 (tile 2i+1)
        LOADA(0, 0); LOADB(0, 0, b0F);
        STAGE_AH(1, k1, 0);
        BARX; LGKM0; PR1; QUADM(0, 0, b0F); PR0; BARX;
        // P2: ds B-nh1; stage buf1-A-h1
        LOADB(0, 1, b1F);
        STAGE_AH(1, k1, 1);
        BARX; LGKM0; PR1; QUADM(0, 1, b1F); PR0; BARX;
        // P3: ds A-mh1; stage buf0-B-h0 (tile 2i+2; buf0-B reads done at P2)
        LOADA(0, 1);
        if (more) STAGE_BH(0, k2, 0);
        BARX; LGKM0; PR1; QUADM(1, 1, b1F); PR0; BARX;
        // P4: stage buf0-B-h1; counted vmcnt -> buf1 (A+B) complete for P5
        if (more) { STAGE_BH(0, k2, 1); VMC(4); } else { VMC(0); }
        BARX; PR1; QUADM(1, 0, b0F); PR0; BARX;
        // ======== K-tile 2i+1 (buf1) ========
        // P5: ds A-mh0 + B-nh0; stage buf0-A-h0 (buf0-A reads done at P3)
        LOADA(1, 0); LOADB(1, 0, b0F);
        if (more) STAGE_AH(0, k2, 0);
        BARX; LGKM0; PR1; QUADM(0, 0, b0F); PR0; BARX;
        // P6: ds B-nh1; stage buf0-A-h1
        LOADB(1, 1, b1F);
        if (more) STAGE_AH(0, k2, 1);
        BARX; LGKM0; PR1; QUADM(0, 1, b1F); PR0; BARX;
        // P7: ds A-mh1; stage buf1-B-h0 (tile 2i+3; buf1-B reads done at P6)
        LOADA(1, 1);
        if (more) STAGE_BH(1, k3, 0);
        BARX; LGKM0; PR1; QUADM(1, 1, b1F); PR0; BARX;
        // P8: stage buf1-B-h1; counted vmcnt -> buf0 (tile 2i+2) complete
        if (more) { STAGE_BH(1, k3, 1); VMC(4); }
        BARX; PR1; QUADM(1, 0, b0F); PR0; BARX;
    }

    // -------- epilogue --------
    const int which = n0 >> 11;          // 0=q 1=k 2=v
    const int bidx  = m0 >> 11;
    const int cb    = (n0 & 2047) + wn * 64;
    const int h     = cb >> 7;
    const int d0    = cb & 127;

    float bcol[4];
#pragma unroll
    for (int nt = 0; nt < 4; ++nt) bcol[nt] = bias[n0 + wn * 64 + nt * 16 + m];

    if (which < 2) {
        short* dst = (which == 0) ? qb : kbf;
        const float post = (which == 0) ? 0.08838834764831845f : 1.0f;
#pragma unroll
        for (int mt = 0; mt < 8; ++mt)
#pragma unroll
            for (int r = 0; r < 4; ++r) {
                int sl = (m0 & 2047) + wm * 128 + mt * 16 + 4 * quad + r;
                const float2* csr = cst + (size_t)sl * HD;
                size_t rowb = ((size_t)(bidx * NH + h) * SEQ + sl) * HD;
#pragma unroll
                for (int nt = 0; nt < 4; ++nt) {
                    float x  = acc[mt][nt][r] + bcol[nt];
                    float px = __shfl_xor(x, 1, 64);   // RoPE pair partner
                    int   d  = d0 + nt * 16 + m;
                    float2 cs = csr[d];
                    float rot = (m & 1) ? fmaf(px, cs.y, x * cs.x)
                                        : (x * cs.x - px * cs.y);
                    dst[rowb + d] = f2bf(rot * post);
                }
            }
    } else {
        // V: per-wave transpose via (dead) staging LDS -> vT [b][h][d][s]
        short* tw = &lds[w * 8192];      // 64 d-rows x 128 s, chunk ^= d&15
#pragma unroll
        for (int mt = 0; mt < 8; ++mt)
#pragma unroll
            for (int nt = 0; nt < 4; ++nt)
#pragma unroll
                for (int r = 0; r < 4; ++r) {
                    int s_l = mt * 16 + 4 * quad + r;
                    int d_l = nt * 16 + m;
                    tw[d_l * 128 + (((s_l >> 3) ^ m) << 3) + (s_l & 7)] =
                        f2bf(acc[mt][nt][r] + bcol[nt]);
                }
        const size_t vbase = (size_t)(bidx * NH + h) * HD * SEQ;
        const int sbase = (m0 & 2047) + wm * 128;
#pragma unroll
        for (int it = 0; it < 16; ++it) {
            int d_l = it * 4 + quad;
            bf16x8 row = *(const bf16x8*)&tw[d_l * 128 + ((m ^ (d_l & 15)) << 3)];
            *(bf16x8*)(vTt + vbase + (size_t)(d0 + d_l) * SEQ + sbase + m * 8) = row;
        }
    }
}

// ---------------------------------------------------------------------------
// MFMA flash attention (unchanged, passing since round 1): 8 waves, q-tile
// 128, KV tile 64 double-buffered, defer-max softmax, cvt_pk, setprio.
// ---------------------------------------------------------------------------
#define AK0 0
#define AK1 8192
#define AV0 16384
#define AV1 24576
#define AP  32768

__global__ __launch_bounds__(512, 4) void attn_mfma_kernel(
    const short* __restrict__ qb, const short* __restrict__ kbf,
    const short* __restrict__ vTt, const float* __restrict__ mask,
    short* __restrict__ ctxb) {
    __shared__ __align__(16) short lds[40960];   // 80 KB

    const int t    = threadIdx.x;
    const int w    = t >> 6;            // 0..7
    const int lane = t & 63;
    const int m    = lane & 15;
    const int quad = lane >> 4;

    const int id  = blockIdx.x;
    const int j   = id >> 3;
    const int bh  = (id & 7) * 4 + (j >> 4);
    const int q0  = (j & 15) * 128;
    const int b   = bh >> 4;
    const int h   = bh & 15;

    const size_t base = (size_t)bh * SEQ * HD;
    const short* kp = kbf + base;        // [s][d]
    const short* vp = vTt + base;        // [d][s]
    const float* mrow = mask + (size_t)b * SEQ;

    size_t kOff[2], vOff[2];
    int kDst[2], vDst[2];
#pragma unroll
    for (int u = 0; u < 2; ++u) {
        int rk = w * 8 + u * 4 + (lane >> 4);
        int ck = (lane & 15) ^ (rk & 7);
        kOff[u] = (size_t)rk * HD + ck * 8;
        kDst[u] = (w * 8 + u * 4) * 128;
        int rv = w * 16 + u * 8 + (lane >> 3);
        int cv = (lane & 7) ^ (rv & 7);
        vOff[u] = (size_t)rv * SEQ + cv * 8;
        vDst[u] = (w * 16 + u * 8) * 64;
    }

    const int srow = q0 + w * 16 + m;
    bf16x8 qh[4];
    {
        const short* qhp = qb + base + (size_t)srow * HD;
#pragma unroll
        for (int c = 0; c < 4; ++c)
            qh[c] = *(const bf16x8*)(qhp + 32 * c + 8 * quad);
    }

    f32x4 O[8];
    float m_i[4], l_p[4];
#pragma unroll
    for (int c = 0; c < 8; ++c) O[c] = (f32x4){0.f, 0.f, 0.f, 0.f};
#pragma unroll
    for (int r = 0; r < 4; ++r) { m_i[r] = -INFINITY; l_p[r] = 0.f; }

    const int sw = m & 7;
    const int pb = AP + w * 1024;
    const int kcb = (m >> 3);
    const int ml  = m & 7;

#pragma unroll
    for (int u = 0; u < 2; ++u) {
        gl_lds16(kp + kOff[u], &lds[AK0 + kDst[u]]);
        gl_lds16(vp + vOff[u], &lds[AV0 + vDst[u]]);
    }

    for (int kt = 0; kt < NT; ++kt) {
        const int cur = kt & 1;
        const int k0  = kt * 64;

        __syncthreads();

        if (kt + 1 < NT) {
            const int nk0 = (kt + 1) * 64;
            const int nb  = cur ^ 1;
#pragma unroll
            for (int u = 0; u < 2; ++u) {
                gl_lds16(kp + (size_t)nk0 * HD + kOff[u],
                         &lds[(nb ? AK1 : AK0) + kDst[u]]);
                gl_lds16(vp + nk0 + vOff[u],
                         &lds[(nb ? AV1 : AV0) + vDst[u]]);
            }
        }

        const short* kb = &lds[cur ? AK1 : AK0];
        const short* vb = &lds[cur ? AV1 : AV0];

        float mk[4];
#pragma unroll
        for (int c2 = 0; c2 < 4; ++c2) mk[c2] = mrow[k0 + 16 * c2 + m];

        f32x4 S[4];
        __builtin_amdgcn_s_setprio(1);
#pragma unroll
        for (int c2 = 0; c2 < 4; ++c2) {
            f32x4 acc = (f32x4){0.f, 0.f, 0.f, 0.f};
#pragma unroll
            for (int c = 0; c < 4; ++c) {
                int pk = (4 * c + quad) ^ sw;
                bf16x8 kf = *(const bf16x8*)&kb[(16 * c2 + m) * 128 + pk * 8];
                acc = __builtin_amdgcn_mfma_f32_16x16x32_bf16(qh[c], kf, acc, 0, 0, 0);
            }
            S[c2] = acc;
        }
        __builtin_amdgcn_s_setprio(0);

        float rm4[4];
#pragma unroll
        for (int r = 0; r < 4; ++r) {
            float s0 = S[0][r] + mk[0];
            float s1 = S[1][r] + mk[1];
            float s2 = S[2][r] + mk[2];
            float s3 = S[3][r] + mk[3];
            S[0][r] = s0; S[1][r] = s1; S[2][r] = s2; S[3][r] = s3;
            float rm = fmaxf(fmaxf(s0, s1), fmaxf(s2, s3));
#pragma unroll
            for (int off = 1; off < 16; off <<= 1)
                rm = fmaxf(rm, __shfl_xor(rm, off, 64));
            rm4[r] = rm;
        }
        int needI = (rm4[0] > m_i[0] + 8.f) | (rm4[1] > m_i[1] + 8.f) |
                    (rm4[2] > m_i[2] + 8.f) | (rm4[3] > m_i[3] + 8.f);
        if (__any(needI)) {
#pragma unroll
            for (int r = 0; r < 4; ++r) {
                float mn = fmaxf(m_i[r], rm4[r]);
                float a  = __expf(m_i[r] - mn);
                m_i[r]   = mn;
                l_p[r]  *= a;
#pragma unroll
                for (int c = 0; c < 8; ++c) O[c][r] *= a;
            }
        }
        float p[4][4];
#pragma unroll
        for (int r = 0; r < 4; ++r) {
#pragma unroll
            for (int c2 = 0; c2 < 4; ++c2) p[c2][r] = __expf(S[c2][r] - m_i[r]);
            l_p[r] += (p[0][r] + p[1][r]) + (p[2][r] + p[3][r]);
        }

#pragma unroll
        for (int c2 = 0; c2 < 4; ++c2) {
#pragma unroll
            for (int jj = 0; jj < 2; ++jj) {
                unsigned pkw;
                asm("v_cvt_pk_bf16_f32 %0, %1, %2"
                    : "=v"(pkw) : "v"(p[c2][2 * jj]), "v"(p[c2][2 * jj + 1]));
                int ql = 4 * quad + 2 * jj;
                int qh2 = ql + 1;
                lds[pb + ql * 64 + (((2 * c2 + kcb) ^ (ql & 7)) << 3) + ml] =
                    (short)(pkw & 0xffffu);
                lds[pb + qh2 * 64 + (((2 * c2 + kcb) ^ (qh2 & 7)) << 3) + ml] =
                    (short)(pkw >> 16);
            }
        }

        __builtin_amdgcn_s_setprio(1);
#pragma unroll
        for (int cc = 0; cc < 2; ++cc) {
            int pv = (4 * cc + quad) ^ sw;
            bf16x8 pf = *(const bf16x8*)&lds[pb + m * 64 + (pv << 3)];
#pragma unroll
            for (int c = 0; c < 8; ++c) {
                bf16x8 vf = *(const bf16x8*)&vb[(16 * c + m) * 64 + pv * 8];
                O[c] = __builtin_amdgcn_mfma_f32_16x16x32_bf16(pf, vf, O[c], 0, 0, 0);
            }
        }
        __builtin_amdgcn_s_setprio(0);
    }

#pragma unroll
    for (int r = 0; r < 4; ++r) {
        float lv = l_p[r];
#pragma unroll
        for (int off = 1; off < 16; off <<= 1) lv += __shfl_xor(lv, off, 64);
        float inv = 1.0f / lv;
        int s = q0 + w * 16 + 4 * quad + r;
        size_t off2 = ((size_t)(b * SEQ + s)) * HID + h * HD;
#pragma unroll
        for (int c = 0; c < 8; ++c)
            ctxb[off2 + 16 * c + m] = f2bf(O[c][r] * inv);
    }
}

// ---------------------------------------------------------------------------
extern "C" void kernel_launch(void* const* d_in, const int* in_sizes, int n_in,
                              void* d_out, int out_size, void* d_ws, size_t ws_size,
                              hipStream_t stream) {
    const float* hs   = (const float*)d_in[0];
    const float* mask = (const float*)d_in[1];
    const float* Wqkv = (const float*)d_in[2];
    const float* bqkv = (const float*)d_in[3];
    const float* Wout = (const float*)d_in[4];
    const float* bout = (const float*)d_in[5];
    float* out = (float*)d_out;

    const size_t qkv_elems = (size_t)NBATCH * NH * SEQ * HD;  // 8.39M
    char* p = (char*)d_ws;
    float2* cst  = (float2*)p; p += (size_t)SEQ * HD * 8;   // fused cos/sin, 2 MB
    short* qbf   = (short*)p; p += qkv_elems * 2;
    short* kbf   = (short*)p; p += qkv_elems * 2;
    short* vTt   = (short*)p; p += qkv_elems * 2;
    short* Wqkvh = (short*)p; p += (size_t)3 * HID * HID * 2;
    short* Wouth = (short*)p; p += (size_t)HID * HID * 2;
    short* Ahs   = (short*)p; p += qkv_elems * 2;   // bf16(hs); aliased ctx after QKV
    short* ctxb  = Ahs;

    // fused prep: RoPE table + bf16 casts of hs / Wqkv / Wout (1 launch)
    prep_kernel<<<2048, 256, 0, stream>>>(hs, Wqkv, Wout, cst, Ahs, Wqkvh, Wouth);

    // QKV: M=4096, N=6144, K=2048 -> 384 blocks of 512 (8-phase 256^2, BK=64)
    gemm256_qkv_kernel<<<384, 512, 0, stream>>>(
        Ahs, Wqkvh, bqkv, qbf, kbf, vTt, cst);

    // attention: 512 XCD-swizzled blocks of 512 threads
    attn_mfma_kernel<<<512, 512, 0, stream>>>(qbf, kbf, vTt, mask, ctxb);

    // out-proj: M=4096, N=2048, K=2048 (m97 structure)
    gemm_out_kernel<<<dim3(16, 32), 256, 0, stream>>>(ctxb, Wouth, bout, out);
}

// Round 10
// 414.435 us; speedup vs baseline: 3.1117x; 1.0191x over previous
//
#include <hip/hip_runtime.h>
#include <math.h>

#define HID    2048
#define NH     16
#define HD     128
#define SEQ    2048
#define NBATCH 2
#define NT     (SEQ / 64)

typedef __attribute__((ext_vector_type(8))) short bf16x8;   // 8 bf16 = 4 VGPRs
typedef __attribute__((ext_vector_type(4))) float f32x4;    // MFMA accumulator

__device__ __forceinline__ short f2bf(float f) {            // fp32 -> bf16 RNE
    union { float f; unsigned u; } x; x.f = f;
    unsigned r = x.u + 0x7fffu + ((x.u >> 16) & 1u);
    return (short)(r >> 16);
}

// async global->LDS, 16 B per lane; LDS dest = wave-uniform base + lane*16
__device__ __forceinline__ void gl_lds16(const short* g, short* l) {
    __builtin_amdgcn_global_load_lds(
        (const __attribute__((address_space(1))) unsigned int*)g,
        (__attribute__((address_space(3))) unsigned int*)l, 16, 0, 0);
}

// ---------------------------------------------------------------------------
// Fused prep kernel: RoPE table + 3x fp32->bf16 casts in ONE launch.
// ---------------------------------------------------------------------------
#define ROPE_N  (SEQ * 64)                       // 131072
#define HS_N4   (NBATCH * SEQ * HID / 4)         // 2097152
#define WQKV_N4 (3 * HID * HID / 4)              // 3145728
#define WOUT_N4 (HID * HID / 4)                  // 1048576

__global__ __launch_bounds__(256) void prep_kernel(
    const float* __restrict__ hs, const float* __restrict__ Wqkv,
    const float* __restrict__ Wout,
    float2* __restrict__ cst, short* __restrict__ Ahs,
    short* __restrict__ Wqkvh, short* __restrict__ Wouth) {
    const long total = (long)ROPE_N + HS_N4 + WQKV_N4 + WOUT_N4;
    for (long idx = (long)blockIdx.x * 256 + threadIdx.x; idx < total;
         idx += (long)gridDim.x * 256) {
        if (idx < ROPE_N) {
            int s = (int)(idx >> 6);
            int i = (int)(idx & 63);
            double inv = pow(10000.0, -(double)i / 64.0);
            float freq = (float)s * (float)inv;
            float2 cs = make_float2(cosf(freq), sinf(freq));
            cst[s * HD + 2 * i]     = cs;
            cst[s * HD + 2 * i + 1] = cs;
        } else if (idx < (long)ROPE_N + HS_N4) {
            long i = idx - ROPE_N;
            float4 v = ((const float4*)hs)[i];
            short4 h;
            h.x = f2bf(v.x); h.y = f2bf(v.y); h.z = f2bf(v.z); h.w = f2bf(v.w);
            *(short4*)(Ahs + 4 * i) = h;
        } else if (idx < (long)ROPE_N + HS_N4 + WQKV_N4) {
            long i = idx - ROPE_N - HS_N4;
            float4 v = ((const float4*)Wqkv)[i];
            short4 h;
            h.x = f2bf(v.x); h.y = f2bf(v.y); h.z = f2bf(v.z); h.w = f2bf(v.w);
            *(short4*)(Wqkvh + 4 * i) = h;
        } else {
            long i = idx - ROPE_N - HS_N4 - WQKV_N4;
            float4 v = ((const float4*)Wout)[i];
            short4 h;
            h.x = f2bf(v.x); h.y = f2bf(v.y); h.z = f2bf(v.z); h.w = f2bf(v.w);
            *(short4*)(Wouth + 4 * i) = h;
        }
    }
}

// ---------------------------------------------------------------------------
// out-proj GEMM (m97 structure, unchanged): C = A.B^T + bias, fp32 out.
// ---------------------------------------------------------------------------
#define LDSA 0
#define LDSB 4096

__global__ __launch_bounds__(256, 3) void gemm_out_kernel(
    const short* __restrict__ Ah, const short* __restrict__ Bh,
    const float* __restrict__ bias, float* __restrict__ C) {
    __shared__ short lds[8192];

    const int t     = threadIdx.x;
    const int w     = t >> 6;
    const int lane  = t & 63;
    const int mfrag = lane & 15;
    const int quad  = lane >> 4;
    const int wm    = (w >> 1) * 64;
    const int wn    = (w & 1) * 64;
    const int m0    = blockIdx.y * 128;
    const int n0    = blockIdx.x * 128;

    const int srow   = lane >> 2;
    const int schunk = (((lane & 3) ^ ((lane >> 3) & 3))) * 8;
    const short* gA0 = Ah + (size_t)(m0 + w * 16 + srow) * HID + schunk;
    const short* gA1 = Ah + (size_t)(m0 + 64 + w * 16 + srow) * HID + schunk;
    const short* gB0 = Bh + (size_t)(n0 + w * 16 + srow) * HID + schunk;
    const short* gB1 = Bh + (size_t)(n0 + 64 + w * 16 + srow) * HID + schunk;
    short* lA0 = &lds[LDSA + (w * 16) * 32];
    short* lA1 = &lds[LDSA + (64 + w * 16) * 32];
    short* lB0 = &lds[LDSB + (w * 16) * 32];
    short* lB1 = &lds[LDSB + (64 + w * 16) * 32];

    const int chA = 8 * (quad ^ ((mfrag >> 1) & 3));  // inverse swizzle

    f32x4 acc[4][4];
#pragma unroll
    for (int i = 0; i < 4; ++i)
#pragma unroll
        for (int j = 0; j < 4; ++j) acc[i][j] = (f32x4){0.f, 0.f, 0.f, 0.f};

    for (int kt = 0; kt < HID; kt += 32) {
        __syncthreads();
        gl_lds16(gA0 + kt, lA0);
        gl_lds16(gA1 + kt, lA1);
        gl_lds16(gB0 + kt, lB0);
        gl_lds16(gB1 + kt, lB1);
        __syncthreads();

        bf16x8 ah[4], bh[4];
#pragma unroll
        for (int mt = 0; mt < 4; ++mt)
            ah[mt] = *(const bf16x8*)&lds[LDSA + (wm + mt * 16 + mfrag) * 32 + chA];
#pragma unroll
        for (int nt = 0; nt < 4; ++nt)
            bh[nt] = *(const bf16x8*)&lds[LDSB + (wn + nt * 16 + mfrag) * 32 + chA];

#pragma unroll
        for (int mt = 0; mt < 4; ++mt)
#pragma unroll
            for (int nt = 0; nt < 4; ++nt)
                acc[mt][nt] = __builtin_amdgcn_mfma_f32_16x16x32_bf16(
                    ah[mt], bh[nt], acc[mt][nt], 0, 0, 0);
    }

    float bcol[4];
#pragma unroll
    for (int nt = 0; nt < 4; ++nt) bcol[nt] = bias[n0 + wn + nt * 16 + mfrag];

#pragma unroll
    for (int mt = 0; mt < 4; ++mt)
#pragma unroll
        for (int r = 0; r < 4; ++r) {
            int mm = m0 + wm + mt * 16 + 4 * quad + r;
#pragma unroll
            for (int nt = 0; nt < 4; ++nt)
                C[(size_t)mm * HID + n0 + wn + nt * 16 + mfrag] =
                    acc[mt][nt][r] + bcol[nt];
        }
}

// ---------------------------------------------------------------------------
// QKV GEMM: 256x256 tile, BK=64, 8-phase schedule (T2+T3+T4+T5 per m201).
// VERIFIED round-5 version (131 us, VGPR 128, MfmaUtil 33%). Register-bound
// to 1 block/CU (round-7 lesson: occupancy bound 4 -> acc spills, 8x slower).
// ---------------------------------------------------------------------------
#define PR1 __builtin_amdgcn_s_setprio(1)
#define PR0 __builtin_amdgcn_s_setprio(0)
#define BARX __builtin_amdgcn_s_barrier()
#define LGKM0 asm volatile("s_waitcnt lgkmcnt(0)" ::: "memory")
#define VMC(n) asm volatile("s_waitcnt vmcnt(" #n ")" ::: "memory")

#define STAGE_AH(bf, ke, hh) { _Pragma("unroll") for (int c = 0; c < 2; ++c) \
    gl_lds16(Ag + (size_t)(((hh) * 2 + c) * 64) * HID + (ke), \
             &lds[(bf) * 32768 + sdst + ((hh) * 2 + c) * 4096]); }
#define STAGE_BH(bf, ke, hh) { _Pragma("unroll") for (int c = 0; c < 2; ++c) \
    gl_lds16(Bg + (size_t)(((hh) * 2 + c) * 64) * HID + (ke), \
             &lds[(bf) * 32768 + 16384 + sdst + ((hh) * 2 + c) * 4096]); }

#define LOADA(bf, mh) { _Pragma("unroll") for (int x = 0; x < 4; ++x) { \
    aF[x][0] = *(const bf16x8*)&lds[(bf) * 32768 + aoff + ((mh) * 4 + x) * 1024 + fc0]; \
    aF[x][1] = *(const bf16x8*)&lds[(bf) * 32768 + aoff + ((mh) * 4 + x) * 1024 + fc1]; } }
#define LOADB(bf, nh, dstF) { _Pragma("unroll") for (int x = 0; x < 2; ++x) { \
    dstF[x][0] = *(const bf16x8*)&lds[(bf) * 32768 + 16384 + boff + ((nh) * 2 + x) * 1024 + fc0]; \
    dstF[x][1] = *(const bf16x8*)&lds[(bf) * 32768 + 16384 + boff + ((nh) * 2 + x) * 1024 + fc1]; } }
#define QUADM(mh, nh, bF) { _Pragma("unroll") for (int x = 0; x < 4; ++x) \
    _Pragma("unroll") for (int y = 0; y < 2; ++y) { \
    acc[(mh) * 4 + x][(nh) * 2 + y] = __builtin_amdgcn_mfma_f32_16x16x32_bf16( \
        aF[x][0], bF[y][0], acc[(mh) * 4 + x][(nh) * 2 + y], 0, 0, 0); \
    acc[(mh) * 4 + x][(nh) * 2 + y] = __builtin_amdgcn_mfma_f32_16x16x32_bf16( \
        aF[x][1], bF[y][1], acc[(mh) * 4 + x][(nh) * 2 + y], 0, 0, 0); } }

__global__ __launch_bounds__(512, 2) void gemm256_qkv_kernel(
    const short* __restrict__ Ah, const short* __restrict__ Bh,
    const float* __restrict__ bias,
    short* __restrict__ qb, short* __restrict__ kbf, short* __restrict__ vTt,
    const float2* __restrict__ cst) {
    __shared__ __align__(16) short lds[65536];   // 128 KB

    const int t    = threadIdx.x;
    const int w    = t >> 6;            // 0..7
    const int lane = t & 63;
    const int m    = lane & 15;
    const int quad = lane >> 4;
    const int wm   = w >> 2;            // 0..1  (M half)
    const int wn   = w & 3;             // 0..3  (N quarter)

    const int swz = (blockIdx.x & 7) * 48 + (blockIdx.x >> 3);
    const int bx  = swz / 16;           // 0..23 -> N
    const int by  = swz % 16;           // 0..15 -> M
    const int m0  = by * 256;
    const int n0  = bx * 256;

    const int srl = lane >> 3;
    const int sch = ((lane & 7) ^ (srl & 7)) * 8;
    const short* Ag = Ah + (size_t)(m0 + w * 8 + srl) * HID + sch;
    const short* Bg = Bh + (size_t)(n0 + w * 8 + srl) * HID + sch;
    const int sdst  = w * 512;          // wave's 8-row stripe (shorts)

    const int key  = m & 7;
    const int fc0  = (quad ^ key) * 8;
    const int fc1  = ((4 + quad) ^ key) * 8;
    const int aoff = (wm * 128 + m) * 64;
    const int boff = (wn * 64 + m) * 64;

    f32x4 acc[8][4];
#pragma unroll
    for (int i = 0; i < 8; ++i)
#pragma unroll
        for (int j = 0; j < 4; ++j) acc[i][j] = (f32x4){0.f, 0.f, 0.f, 0.f};

    bf16x8 aF[4][2], b0F[2][2], b1F[2][2];

    STAGE_AH(0, 0, 0); STAGE_AH(0, 0, 1);
    STAGE_BH(0, 0, 0); STAGE_BH(0, 0, 1);
    STAGE_BH(1, 64, 0); STAGE_BH(1, 64, 1);
    VMC(4); BARX;

    const int NIT = HID / 128;          // 16 iterations, 2 K-tiles each
#pragma unroll 1
    for (int i = 0; i < NIT; ++i) {
        const int k1   = i * 128 + 64;
        const int k2   = (i + 1) * 128;
        const int k3   = k2 + 64;
        const bool more = (i + 1 < NIT);
        LOADA(0, 0); LOADB(0, 0, b0F);
        STAGE_AH(1, k1, 0);
        BARX; LGKM0; PR1; QUADM(0, 0, b0F); PR0; BARX;
        LOADB(0, 1, b1F);
        STAGE_AH(1, k1, 1);
        BARX; LGKM0; PR1; QUADM(0, 1, b1F); PR0; BARX;
        LOADA(0, 1);
        if (more) STAGE_BH(0, k2, 0);
        BARX; LGKM0; PR1; QUADM(1, 1, b1F); PR0; BARX;
        if (more) { STAGE_BH(0, k2, 1); VMC(4); } else { VMC(0); }
        BARX; PR1; QUADM(1, 0, b0F); PR0; BARX;
        LOADA(1, 0); LOADB(1, 0, b0F);
        if (more) STAGE_AH(0, k2, 0);
        BARX; LGKM0; PR1; QUADM(0, 0, b0F); PR0; BARX;
        LOADB(1, 1, b1F);
        if (more) STAGE_AH(0, k2, 1);
        BARX; LGKM0; PR1; QUADM(0, 1, b1F); PR0; BARX;
        LOADA(1, 1);
        if (more) STAGE_BH(1, k3, 0);
        BARX; LGKM0; PR1; QUADM(1, 1, b1F); PR0; BARX;
        if (more) { STAGE_BH(1, k3, 1); VMC(4); }
        BARX; PR1; QUADM(1, 0, b0F); PR0; BARX;
    }

    const int which = n0 >> 11;          // 0=q 1=k 2=v
    const int bidx  = m0 >> 11;
    const int cb    = (n0 & 2047) + wn * 64;
    const int h     = cb >> 7;
    const int d0    = cb & 127;

    float bcol[4];
#pragma unroll
    for (int nt = 0; nt < 4; ++nt) bcol[nt] = bias[n0 + wn * 64 + nt * 16 + m];

    if (which < 2) {
        short* dst = (which == 0) ? qb : kbf;
        const float post = (which == 0) ? 0.08838834764831845f : 1.0f;
#pragma unroll
        for (int mt = 0; mt < 8; ++mt)
#pragma unroll
            for (int r = 0; r < 4; ++r) {
                int sl = (m0 & 2047) + wm * 128 + mt * 16 + 4 * quad + r;
                const float2* csr = cst + (size_t)sl * HD;
                size_t rowb = ((size_t)(bidx * NH + h) * SEQ + sl) * HD;
#pragma unroll
                for (int nt = 0; nt < 4; ++nt) {
                    float x  = acc[mt][nt][r] + bcol[nt];
                    float px = __shfl_xor(x, 1, 64);   // RoPE pair partner
                    int   d  = d0 + nt * 16 + m;
                    float2 cs = csr[d];
                    float rot = (m & 1) ? fmaf(px, cs.y, x * cs.x)
                                        : (x * cs.x - px * cs.y);
                    dst[rowb + d] = f2bf(rot * post);
                }
            }
    } else {
        short* tw = &lds[w * 8192];      // 64 d-rows x 128 s, chunk ^= d&15
#pragma unroll
        for (int mt = 0; mt < 8; ++mt)
#pragma unroll
            for (int nt = 0; nt < 4; ++nt)
#pragma unroll
                for (int r = 0; r < 4; ++r) {
                    int s_l = mt * 16 + 4 * quad + r;
                    int d_l = nt * 16 + m;
                    tw[d_l * 128 + (((s_l >> 3) ^ m) << 3) + (s_l & 7)] =
                        f2bf(acc[mt][nt][r] + bcol[nt]);
                }
        const size_t vbase = (size_t)(bidx * NH + h) * HD * SEQ;
        const int sbase = (m0 & 2047) + wm * 128;
#pragma unroll
        for (int it = 0; it < 16; ++it) {
            int d_l = it * 4 + quad;
            bf16x8 row = *(const bf16x8*)&tw[d_l * 128 + ((m ^ (d_l & 15)) << 3)];
            *(bf16x8*)(vTt + vbase + (size_t)(d0 + d_l) * SEQ + sbase + m * 8) = row;
        }
    }
}

// ---------------------------------------------------------------------------
// MFMA flash attention (verified since round 1): 8 waves, q-tile 128,
// KV tile 64 double-buffered, defer-max softmax, cvt_pk, setprio.
// ---------------------------------------------------------------------------
#define AK0 0
#define AK1 8192
#define AV0 16384
#define AV1 24576
#define AP  32768

__global__ __launch_bounds__(512, 4) void attn_mfma_kernel(
    const short* __restrict__ qb, const short* __restrict__ kbf,
    const short* __restrict__ vTt, const float* __restrict__ mask,
    short* __restrict__ ctxb) {
    __shared__ __align__(16) short lds[40960];   // 80 KB

    const int t    = threadIdx.x;
    const int w    = t >> 6;            // 0..7
    const int lane = t & 63;
    const int m    = lane & 15;
    const int quad = lane >> 4;

    const int id  = blockIdx.x;
    const int j   = id >> 3;
    const int bh  = (id & 7) * 4 + (j >> 4);
    const int q0  = (j & 15) * 128;
    const int b   = bh >> 4;
    const int h   = bh & 15;

    const size_t base = (size_t)bh * SEQ * HD;
    const short* kp = kbf + base;        // [s][d]
    const short* vp = vTt + base;        // [d][s]
    const float* mrow = mask + (size_t)b * SEQ;

    size_t kOff[2], vOff[2];
    int kDst[2], vDst[2];
#pragma unroll
    for (int u = 0; u < 2; ++u) {
        int rk = w * 8 + u * 4 + (lane >> 4);
        int ck = (lane & 15) ^ (rk & 7);
        kOff[u] = (size_t)rk * HD + ck * 8;
        kDst[u] = (w * 8 + u * 4) * 128;
        int rv = w * 16 + u * 8 + (lane >> 3);
        int cv = (lane & 7) ^ (rv & 7);
        vOff[u] = (size_t)rv * SEQ + cv * 8;
        vDst[u] = (w * 16 + u * 8) * 64;
    }

    const int srow = q0 + w * 16 + m;
    bf16x8 qh[4];
    {
        const short* qhp = qb + base + (size_t)srow * HD;
#pragma unroll
        for (int c = 0; c < 4; ++c)
            qh[c] = *(const bf16x8*)(qhp + 32 * c + 8 * quad);
    }

    f32x4 O[8];
    float m_i[4], l_p[4];
#pragma unroll
    for (int c = 0; c < 8; ++c) O[c] = (f32x4){0.f, 0.f, 0.f, 0.f};
#pragma unroll
    for (int r = 0; r < 4; ++r) { m_i[r] = -INFINITY; l_p[r] = 0.f; }

    const int sw = m & 7;
    const int pb = AP + w * 1024;
    const int kcb = (m >> 3);
    const int ml  = m & 7;

#pragma unroll
    for (int u = 0; u < 2; ++u) {
        gl_lds16(kp + kOff[u], &lds[AK0 + kDst[u]]);
        gl_lds16(vp + vOff[u], &lds[AV0 + vDst[u]]);
    }

    for (int kt = 0; kt < NT; ++kt) {
        const int cur = kt & 1;
        const int k0  = kt * 64;

        __syncthreads();

        if (kt + 1 < NT) {
            const int nk0 = (kt + 1) * 64;
            const int nb  = cur ^ 1;
#pragma unroll
            for (int u = 0; u < 2; ++u) {
                gl_lds16(kp + (size_t)nk0 * HD + kOff[u],
                         &lds[(nb ? AK1 : AK0) + kDst[u]]);
                gl_lds16(vp + nk0 + vOff[u],
                         &lds[(nb ? AV1 : AV0) + vDst[u]]);
            }
        }

        const short* kb = &lds[cur ? AK1 : AK0];
        const short* vb = &lds[cur ? AV1 : AV0];

        float mk[4];
#pragma unroll
        for (int c2 = 0; c2 < 4; ++c2) mk[c2] = mrow[k0 + 16 * c2 + m];

        f32x4 S[4];
        __builtin_amdgcn_s_setprio(1);
#pragma unroll
        for (int c2 = 0; c2 < 4; ++c2) {
            f32x4 acc = (f32x4){0.f, 0.f, 0.f, 0.f};
#pragma unroll
            for (int c = 0; c < 4; ++c) {
                int pk = (4 * c + quad) ^ sw;
                bf16x8 kf = *(const bf16x8*)&kb[(16 * c2 + m) * 128 + pk * 8];
                acc = __builtin_amdgcn_mfma_f32_16x16x32_bf16(qh[c], kf, acc, 0, 0, 0);
            }
            S[c2] = acc;
        }
        __builtin_amdgcn_s_setprio(0);

        float rm4[4];
#pragma unroll
        for (int r = 0; r < 4; ++r) {
            float s0 = S[0][r] + mk[0];
            float s1 = S[1][r] + mk[1];
            float s2 = S[2][r] + mk[2];
            float s3 = S[3][r] + mk[3];
            S[0][r] = s0; S[1][r] = s1; S[2][r] = s2; S[3][r] = s3;
            float rm = fmaxf(fmaxf(s0, s1), fmaxf(s2, s3));
#pragma unroll
            for (int off = 1; off < 16; off <<= 1)
                rm = fmaxf(rm, __shfl_xor(rm, off, 64));
            rm4[r] = rm;
        }
        int needI = (rm4[0] > m_i[0] + 8.f) | (rm4[1] > m_i[1] + 8.f) |
                    (rm4[2] > m_i[2] + 8.f) | (rm4[3] > m_i[3] + 8.f);
        if (__any(needI)) {
#pragma unroll
            for (int r = 0; r < 4; ++r) {
                float mn = fmaxf(m_i[r], rm4[r]);
                float a  = __expf(m_i[r] - mn);
                m_i[r]   = mn;
                l_p[r]  *= a;
#pragma unroll
                for (int c = 0; c < 8; ++c) O[c][r] *= a;
            }
        }
        float p[4][4];
#pragma unroll
        for (int r = 0; r < 4; ++r) {
#pragma unroll
            for (int c2 = 0; c2 < 4; ++c2) p[c2][r] = __expf(S[c2][r] - m_i[r]);
            l_p[r] += (p[0][r] + p[1][r]) + (p[2][r] + p[3][r]);
        }

#pragma unroll
        for (int c2 = 0; c2 < 4; ++c2) {
#pragma unroll
            for (int jj = 0; jj < 2; ++jj) {
                unsigned pkw;
                asm("v_cvt_pk_bf16_f32 %0, %1, %2"
                    : "=v"(pkw) : "v"(p[c2][2 * jj]), "v"(p[c2][2 * jj + 1]));
                int ql = 4 * quad + 2 * jj;
                int qh2 = ql + 1;
                lds[pb + ql * 64 + (((2 * c2 + kcb) ^ (ql & 7)) << 3) + ml] =
                    (short)(pkw & 0xffffu);
                lds[pb + qh2 * 64 + (((2 * c2 + kcb) ^ (qh2 & 7)) << 3) + ml] =
                    (short)(pkw >> 16);
            }
        }

        __builtin_amdgcn_s_setprio(1);
#pragma unroll
        for (int cc = 0; cc < 2; ++cc) {
            int pv = (4 * cc + quad) ^ sw;
            bf16x8 pf = *(const bf16x8*)&lds[pb + m * 64 + (pv << 3)];
#pragma unroll
            for (int c = 0; c < 8; ++c) {
                bf16x8 vf = *(const bf16x8*)&vb[(16 * c + m) * 64 + pv * 8];
                O[c] = __builtin_amdgcn_mfma_f32_16x16x32_bf16(pf, vf, O[c], 0, 0, 0);
            }
        }
        __builtin_amdgcn_s_setprio(0);
    }

#pragma unroll
    for (int r = 0; r < 4; ++r) {
        float lv = l_p[r];
#pragma unroll
        for (int off = 1; off < 16; off <<= 1) lv += __shfl_xor(lv, off, 64);
        float inv = 1.0f / lv;
        int s = q0 + w * 16 + 4 * quad + r;
        size_t off2 = ((size_t)(b * SEQ + s)) * HID + h * HD;
#pragma unroll
        for (int c = 0; c < 8; ++c)
            ctxb[off2 + 16 * c + m] = f2bf(O[c][r] * inv);
    }
}

// ---------------------------------------------------------------------------
extern "C" void kernel_launch(void* const* d_in, const int* in_sizes, int n_in,
                              void* d_out, int out_size, void* d_ws, size_t ws_size,
                              hipStream_t stream) {
    const float* hs   = (const float*)d_in[0];
    const float* mask = (const float*)d_in[1];
    const float* Wqkv = (const float*)d_in[2];
    const float* bqkv = (const float*)d_in[3];
    const float* Wout = (const float*)d_in[4];
    const float* bout = (const float*)d_in[5];
    float* out = (float*)d_out;

    const size_t qkv_elems = (size_t)NBATCH * NH * SEQ * HD;  // 8.39M
    char* p = (char*)d_ws;
    float2* cst  = (float2*)p; p += (size_t)SEQ * HD * 8;   // fused cos/sin, 2 MB
    short* qbf   = (short*)p; p += qkv_elems * 2;
    short* kbf   = (short*)p; p += qkv_elems * 2;
    short* vTt   = (short*)p; p += qkv_elems * 2;
    short* Wqkvh = (short*)p; p += (size_t)3 * HID * HID * 2;
    short* Wouth = (short*)p; p += (size_t)HID * HID * 2;
    short* Ahs   = (short*)p; p += qkv_elems * 2;   // bf16(hs); aliased ctx after QKV
    short* ctxb  = Ahs;

    // fused prep: RoPE table + bf16 casts of hs / Wqkv / Wout (1 launch)
    prep_kernel<<<2048, 256, 0, stream>>>(hs, Wqkv, Wout, cst, Ahs, Wqkvh, Wouth);

    // QKV: M=4096, N=6144, K=2048 -> 384 blocks of 512 (8-phase 256^2, BK=64)
    gemm256_qkv_kernel<<<384, 512, 0, stream>>>(
        Ahs, Wqkvh, bqkv, qbf, kbf, vTt, cst);

    // attention: 512 XCD-swizzled blocks of 512 threads
    attn_mfma_kernel<<<512, 512, 0, stream>>>(qbf, kbf, vTt, mask, ctxb);

    // out-proj: M=4096, N=2048, K=2048 (m97 structure)
    gemm_out_kernel<<<dim3(16, 32), 256, 0, stream>>>(ctxb, Wouth, bout, out);
}

// Round 11
// 391.484 us; speedup vs baseline: 3.2941x; 1.0586x over previous
//
#include <hip/hip_runtime.h>
#include <math.h>

#define HID    2048
#define NH     16
#define HD     128
#define SEQ    2048
#define NBATCH 2
#define NT     (SEQ / 64)

typedef __attribute__((ext_vector_type(8))) short bf16x8;   // 8 bf16 = 4 VGPRs
typedef __attribute__((ext_vector_type(4))) float f32x4;    // MFMA accumulator

__device__ __forceinline__ short f2bf(float f) {            // fp32 -> bf16 RNE
    union { float f; unsigned u; } x; x.f = f;
    unsigned r = x.u + 0x7fffu + ((x.u >> 16) & 1u);
    return (short)(r >> 16);
}

// async global->LDS, 16 B per lane; LDS dest = wave-uniform base + lane*16
__device__ __forceinline__ void gl_lds16(const short* g, short* l) {
    __builtin_amdgcn_global_load_lds(
        (const __attribute__((address_space(1))) unsigned int*)g,
        (__attribute__((address_space(3))) unsigned int*)l, 16, 0, 0);
}

// ---------------------------------------------------------------------------
// Fused prep kernel: RoPE table + 3x fp32->bf16 casts in ONE launch.
// ---------------------------------------------------------------------------
#define ROPE_N  (SEQ * 64)                       // 131072
#define HS_N4   (NBATCH * SEQ * HID / 4)         // 2097152
#define WQKV_N4 (3 * HID * HID / 4)              // 3145728
#define WOUT_N4 (HID * HID / 4)                  // 1048576

__global__ __launch_bounds__(256) void prep_kernel(
    const float* __restrict__ hs, const float* __restrict__ Wqkv,
    const float* __restrict__ Wout,
    float2* __restrict__ cst, short* __restrict__ Ahs,
    short* __restrict__ Wqkvh, short* __restrict__ Wouth) {
    const long total = (long)ROPE_N + HS_N4 + WQKV_N4 + WOUT_N4;
    for (long idx = (long)blockIdx.x * 256 + threadIdx.x; idx < total;
         idx += (long)gridDim.x * 256) {
        if (idx < ROPE_N) {
            int s = (int)(idx >> 6);
            int i = (int)(idx & 63);
            double inv = pow(10000.0, -(double)i / 64.0);
            float freq = (float)s * (float)inv;
            float2 cs = make_float2(cosf(freq), sinf(freq));
            cst[s * HD + 2 * i]     = cs;
            cst[s * HD + 2 * i + 1] = cs;
        } else if (idx < (long)ROPE_N + HS_N4) {
            long i = idx - ROPE_N;
            float4 v = ((const float4*)hs)[i];
            short4 h;
            h.x = f2bf(v.x); h.y = f2bf(v.y); h.z = f2bf(v.z); h.w = f2bf(v.w);
            *(short4*)(Ahs + 4 * i) = h;
        } else if (idx < (long)ROPE_N + HS_N4 + WQKV_N4) {
            long i = idx - ROPE_N - HS_N4;
            float4 v = ((const float4*)Wqkv)[i];
            short4 h;
            h.x = f2bf(v.x); h.y = f2bf(v.y); h.z = f2bf(v.z); h.w = f2bf(v.w);
            *(short4*)(Wqkvh + 4 * i) = h;
        } else {
            long i = idx - ROPE_N - HS_N4 - WQKV_N4;
            float4 v = ((const float4*)Wout)[i];
            short4 h;
            h.x = f2bf(v.x); h.y = f2bf(v.y); h.z = f2bf(v.z); h.w = f2bf(v.w);
            *(short4*)(Wouth + 4 * i) = h;
        }
    }
}

// ---------------------------------------------------------------------------
// out-proj GEMM (m97 structure, unchanged): C = A.B^T + bias, fp32 out.
// ---------------------------------------------------------------------------
#define LDSA 0
#define LDSB 4096

__global__ __launch_bounds__(256, 3) void gemm_out_kernel(
    const short* __restrict__ Ah, const short* __restrict__ Bh,
    const float* __restrict__ bias, float* __restrict__ C) {
    __shared__ short lds[8192];

    const int t     = threadIdx.x;
    const int w     = t >> 6;
    const int lane  = t & 63;
    const int mfrag = lane & 15;
    const int quad  = lane >> 4;
    const int wm    = (w >> 1) * 64;
    const int wn    = (w & 1) * 64;
    const int m0    = blockIdx.y * 128;
    const int n0    = blockIdx.x * 128;

    const int srow   = lane >> 2;
    const int schunk = (((lane & 3) ^ ((lane >> 3) & 3))) * 8;
    const short* gA0 = Ah + (size_t)(m0 + w * 16 + srow) * HID + schunk;
    const short* gA1 = Ah + (size_t)(m0 + 64 + w * 16 + srow) * HID + schunk;
    const short* gB0 = Bh + (size_t)(n0 + w * 16 + srow) * HID + schunk;
    const short* gB1 = Bh + (size_t)(n0 + 64 + w * 16 + srow) * HID + schunk;
    short* lA0 = &lds[LDSA + (w * 16) * 32];
    short* lA1 = &lds[LDSA + (64 + w * 16) * 32];
    short* lB0 = &lds[LDSB + (w * 16) * 32];
    short* lB1 = &lds[LDSB + (64 + w * 16) * 32];

    const int chA = 8 * (quad ^ ((mfrag >> 1) & 3));  // inverse swizzle

    f32x4 acc[4][4];
#pragma unroll
    for (int i = 0; i < 4; ++i)
#pragma unroll
        for (int j = 0; j < 4; ++j) acc[i][j] = (f32x4){0.f, 0.f, 0.f, 0.f};

    for (int kt = 0; kt < HID; kt += 32) {
        __syncthreads();
        gl_lds16(gA0 + kt, lA0);
        gl_lds16(gA1 + kt, lA1);
        gl_lds16(gB0 + kt, lB0);
        gl_lds16(gB1 + kt, lB1);
        __syncthreads();

        bf16x8 ah[4], bh[4];
#pragma unroll
        for (int mt = 0; mt < 4; ++mt)
            ah[mt] = *(const bf16x8*)&lds[LDSA + (wm + mt * 16 + mfrag) * 32 + chA];
#pragma unroll
        for (int nt = 0; nt < 4; ++nt)
            bh[nt] = *(const bf16x8*)&lds[LDSB + (wn + nt * 16 + mfrag) * 32 + chA];

#pragma unroll
        for (int mt = 0; mt < 4; ++mt)
#pragma unroll
            for (int nt = 0; nt < 4; ++nt)
                acc[mt][nt] = __builtin_amdgcn_mfma_f32_16x16x32_bf16(
                    ah[mt], bh[nt], acc[mt][nt], 0, 0, 0);
    }

    float bcol[4];
#pragma unroll
    for (int nt = 0; nt < 4; ++nt) bcol[nt] = bias[n0 + wn + nt * 16 + mfrag];

#pragma unroll
    for (int mt = 0; mt < 4; ++mt)
#pragma unroll
        for (int r = 0; r < 4; ++r) {
            int mm = m0 + wm + mt * 16 + 4 * quad + r;
#pragma unroll
            for (int nt = 0; nt < 4; ++nt)
                C[(size_t)mm * HID + n0 + wn + nt * 16 + mfrag] =
                    acc[mt][nt][r] + bcol[nt];
        }
}

// ---------------------------------------------------------------------------
// QKV GEMM: 256x256 tile, BK=64, 8-phase schedule (T2+T3+T4+T5 per m201).
// VERIFIED round-5 version (131 us, VGPR 128, MfmaUtil 33%). Register-bound
// to 1 block/CU (round-7 lesson: occupancy bound 4 -> acc spills, 8x slower).
// ---------------------------------------------------------------------------
#define PR1 __builtin_amdgcn_s_setprio(1)
#define PR0 __builtin_amdgcn_s_setprio(0)
#define BARX __builtin_amdgcn_s_barrier()
#define LGKM0 asm volatile("s_waitcnt lgkmcnt(0)" ::: "memory")
#define VMC(n) asm volatile("s_waitcnt vmcnt(" #n ")" ::: "memory")

#define STAGE_AH(bf, ke, hh) { _Pragma("unroll") for (int c = 0; c < 2; ++c) \
    gl_lds16(Ag + (size_t)(((hh) * 2 + c) * 64) * HID + (ke), \
             &lds[(bf) * 32768 + sdst + ((hh) * 2 + c) * 4096]); }
#define STAGE_BH(bf, ke, hh) { _Pragma("unroll") for (int c = 0; c < 2; ++c) \
    gl_lds16(Bg + (size_t)(((hh) * 2 + c) * 64) * HID + (ke), \
             &lds[(bf) * 32768 + 16384 + sdst + ((hh) * 2 + c) * 4096]); }

#define LOADA(bf, mh) { _Pragma("unroll") for (int x = 0; x < 4; ++x) { \
    aF[x][0] = *(const bf16x8*)&lds[(bf) * 32768 + aoff + ((mh) * 4 + x) * 1024 + fc0]; \
    aF[x][1] = *(const bf16x8*)&lds[(bf) * 32768 + aoff + ((mh) * 4 + x) * 1024 + fc1]; } }
#define LOADB(bf, nh, dstF) { _Pragma("unroll") for (int x = 0; x < 2; ++x) { \
    dstF[x][0] = *(const bf16x8*)&lds[(bf) * 32768 + 16384 + boff + ((nh) * 2 + x) * 1024 + fc0]; \
    dstF[x][1] = *(const bf16x8*)&lds[(bf) * 32768 + 16384 + boff + ((nh) * 2 + x) * 1024 + fc1]; } }
#define QUADM(mh, nh, bF) { _Pragma("unroll") for (int x = 0; x < 4; ++x) \
    _Pragma("unroll") for (int y = 0; y < 2; ++y) { \
    acc[(mh) * 4 + x][(nh) * 2 + y] = __builtin_amdgcn_mfma_f32_16x16x32_bf16( \
        aF[x][0], bF[y][0], acc[(mh) * 4 + x][(nh) * 2 + y], 0, 0, 0); \
    acc[(mh) * 4 + x][(nh) * 2 + y] = __builtin_amdgcn_mfma_f32_16x16x32_bf16( \
        aF[x][1], bF[y][1], acc[(mh) * 4 + x][(nh) * 2 + y], 0, 0, 0); } }

__global__ __launch_bounds__(512, 2) void gemm256_qkv_kernel(
    const short* __restrict__ Ah, const short* __restrict__ Bh,
    const float* __restrict__ bias,
    short* __restrict__ qb, short* __restrict__ kbf, short* __restrict__ vTt,
    const float2* __restrict__ cst) {
    __shared__ __align__(16) short lds[65536];   // 128 KB

    const int t    = threadIdx.x;
    const int w    = t >> 6;            // 0..7
    const int lane = t & 63;
    const int m    = lane & 15;
    const int quad = lane >> 4;
    const int wm   = w >> 2;            // 0..1  (M half)
    const int wn   = w & 3;             // 0..3  (N quarter)

    const int swz = (blockIdx.x & 7) * 48 + (blockIdx.x >> 3);
    const int bx  = swz / 16;           // 0..23 -> N
    const int by  = swz % 16;           // 0..15 -> M
    const int m0  = by * 256;
    const int n0  = bx * 256;

    const int srl = lane >> 3;
    const int sch = ((lane & 7) ^ (srl & 7)) * 8;
    const short* Ag = Ah + (size_t)(m0 + w * 8 + srl) * HID + sch;
    const short* Bg = Bh + (size_t)(n0 + w * 8 + srl) * HID + sch;
    const int sdst  = w * 512;          // wave's 8-row stripe (shorts)

    const int key  = m & 7;
    const int fc0  = (quad ^ key) * 8;
    const int fc1  = ((4 + quad) ^ key) * 8;
    const int aoff = (wm * 128 + m) * 64;
    const int boff = (wn * 64 + m) * 64;

    f32x4 acc[8][4];
#pragma unroll
    for (int i = 0; i < 8; ++i)
#pragma unroll
        for (int j = 0; j < 4; ++j) acc[i][j] = (f32x4){0.f, 0.f, 0.f, 0.f};

    bf16x8 aF[4][2], b0F[2][2], b1F[2][2];

    STAGE_AH(0, 0, 0); STAGE_AH(0, 0, 1);
    STAGE_BH(0, 0, 0); STAGE_BH(0, 0, 1);
    STAGE_BH(1, 64, 0); STAGE_BH(1, 64, 1);
    VMC(4); BARX;

    const int NIT = HID / 128;          // 16 iterations, 2 K-tiles each
#pragma unroll 1
    for (int i = 0; i < NIT; ++i) {
        const int k1   = i * 128 + 64;
        const int k2   = (i + 1) * 128;
        const int k3   = k2 + 64;
        const bool more = (i + 1 < NIT);
        LOADA(0, 0); LOADB(0, 0, b0F);
        STAGE_AH(1, k1, 0);
        BARX; LGKM0; PR1; QUADM(0, 0, b0F); PR0; BARX;
        LOADB(0, 1, b1F);
        STAGE_AH(1, k1, 1);
        BARX; LGKM0; PR1; QUADM(0, 1, b1F); PR0; BARX;
        LOADA(0, 1);
        if (more) STAGE_BH(0, k2, 0);
        BARX; LGKM0; PR1; QUADM(1, 1, b1F); PR0; BARX;
        if (more) { STAGE_BH(0, k2, 1); VMC(4); } else { VMC(0); }
        BARX; PR1; QUADM(1, 0, b0F); PR0; BARX;
        LOADA(1, 0); LOADB(1, 0, b0F);
        if (more) STAGE_AH(0, k2, 0);
        BARX; LGKM0; PR1; QUADM(0, 0, b0F); PR0; BARX;
        LOADB(1, 1, b1F);
        if (more) STAGE_AH(0, k2, 1);
        BARX; LGKM0; PR1; QUADM(0, 1, b1F); PR0; BARX;
        LOADA(1, 1);
        if (more) STAGE_BH(1, k3, 0);
        BARX; LGKM0; PR1; QUADM(1, 1, b1F); PR0; BARX;
        if (more) { STAGE_BH(1, k3, 1); VMC(4); }
        BARX; PR1; QUADM(1, 0, b0F); PR0; BARX;
    }

    const int which = n0 >> 11;          // 0=q 1=k 2=v
    const int bidx  = m0 >> 11;
    const int cb    = (n0 & 2047) + wn * 64;
    const int h     = cb >> 7;
    const int d0    = cb & 127;

    float bcol[4];
#pragma unroll
    for (int nt = 0; nt < 4; ++nt) bcol[nt] = bias[n0 + wn * 64 + nt * 16 + m];

    if (which < 2) {
        short* dst = (which == 0) ? qb : kbf;
        const float post = (which == 0) ? 0.08838834764831845f : 1.0f;
#pragma unroll
        for (int mt = 0; mt < 8; ++mt)
#pragma unroll
            for (int r = 0; r < 4; ++r) {
                int sl = (m0 & 2047) + wm * 128 + mt * 16 + 4 * quad + r;
                const float2* csr = cst + (size_t)sl * HD;
                size_t rowb = ((size_t)(bidx * NH + h) * SEQ + sl) * HD;
#pragma unroll
                for (int nt = 0; nt < 4; ++nt) {
                    float x  = acc[mt][nt][r] + bcol[nt];
                    float px = __shfl_xor(x, 1, 64);   // RoPE pair partner
                    int   d  = d0 + nt * 16 + m;
                    float2 cs = csr[d];
                    float rot = (m & 1) ? fmaf(px, cs.y, x * cs.x)
                                        : (x * cs.x - px * cs.y);
                    dst[rowb + d] = f2bf(rot * post);
                }
            }
    } else {
        short* tw = &lds[w * 8192];      // 64 d-rows x 128 s, chunk ^= d&15
#pragma unroll
        for (int mt = 0; mt < 8; ++mt)
#pragma unroll
            for (int nt = 0; nt < 4; ++nt)
#pragma unroll
                for (int r = 0; r < 4; ++r) {
                    int s_l = mt * 16 + 4 * quad + r;
                    int d_l = nt * 16 + m;
                    tw[d_l * 128 + (((s_l >> 3) ^ m) << 3) + (s_l & 7)] =
                        f2bf(acc[mt][nt][r] + bcol[nt]);
                }
        const size_t vbase = (size_t)(bidx * NH + h) * HD * SEQ;
        const int sbase = (m0 & 2047) + wm * 128;
#pragma unroll
        for (int it = 0; it < 16; ++it) {
            int d_l = it * 4 + quad;
            bf16x8 row = *(const bf16x8*)&tw[d_l * 128 + ((m ^ (d_l & 15)) << 3)];
            *(bf16x8*)(vTt + vbase + (size_t)(d0 + d_l) * SEQ + sbase + m * 8) = row;
        }
    }
}

// ---------------------------------------------------------------------------
// MFMA flash attention (verified structure since round 1): 8 waves, q-tile
// 128, KV tile 64 double-buffered, defer-max softmax, cvt_pk, setprio.
// Round-11 change (exact-equivalent): the 16-shfl row-max reduce moved
// INSIDE the defer-max branch. rm > m_i+8  <=>  __any(rloc > m_i+8), since
// rm = max over lanes of rloc. Common path (branch not taken): no lane
// exceeded m_i+8 -> defer invariant holds with m_i unchanged -> p values
// bit-identical to before; branch taken: identical code to before.
// Saves 16 shfl_xor + wait chains per tile on ~90% of the 32 tiles.
// ---------------------------------------------------------------------------
#define AK0 0
#define AK1 8192
#define AV0 16384
#define AV1 24576
#define AP  32768

__global__ __launch_bounds__(512, 4) void attn_mfma_kernel(
    const short* __restrict__ qb, const short* __restrict__ kbf,
    const short* __restrict__ vTt, const float* __restrict__ mask,
    short* __restrict__ ctxb) {
    __shared__ __align__(16) short lds[40960];   // 80 KB

    const int t    = threadIdx.x;
    const int w    = t >> 6;            // 0..7
    const int lane = t & 63;
    const int m    = lane & 15;
    const int quad = lane >> 4;

    const int id  = blockIdx.x;
    const int j   = id >> 3;
    const int bh  = (id & 7) * 4 + (j >> 4);
    const int q0  = (j & 15) * 128;
    const int b   = bh >> 4;
    const int h   = bh & 15;

    const size_t base = (size_t)bh * SEQ * HD;
    const short* kp = kbf + base;        // [s][d]
    const short* vp = vTt + base;        // [d][s]
    const float* mrow = mask + (size_t)b * SEQ;

    size_t kOff[2], vOff[2];
    int kDst[2], vDst[2];
#pragma unroll
    for (int u = 0; u < 2; ++u) {
        int rk = w * 8 + u * 4 + (lane >> 4);
        int ck = (lane & 15) ^ (rk & 7);
        kOff[u] = (size_t)rk * HD + ck * 8;
        kDst[u] = (w * 8 + u * 4) * 128;
        int rv = w * 16 + u * 8 + (lane >> 3);
        int cv = (lane & 7) ^ (rv & 7);
        vOff[u] = (size_t)rv * SEQ + cv * 8;
        vDst[u] = (w * 16 + u * 8) * 64;
    }

    const int srow = q0 + w * 16 + m;
    bf16x8 qh[4];
    {
        const short* qhp = qb + base + (size_t)srow * HD;
#pragma unroll
        for (int c = 0; c < 4; ++c)
            qh[c] = *(const bf16x8*)(qhp + 32 * c + 8 * quad);
    }

    f32x4 O[8];
    float m_i[4], l_p[4];
#pragma unroll
    for (int c = 0; c < 8; ++c) O[c] = (f32x4){0.f, 0.f, 0.f, 0.f};
#pragma unroll
    for (int r = 0; r < 4; ++r) { m_i[r] = -INFINITY; l_p[r] = 0.f; }

    const int sw = m & 7;
    const int pb = AP + w * 1024;
    const int kcb = (m >> 3);
    const int ml  = m & 7;

#pragma unroll
    for (int u = 0; u < 2; ++u) {
        gl_lds16(kp + kOff[u], &lds[AK0 + kDst[u]]);
        gl_lds16(vp + vOff[u], &lds[AV0 + vDst[u]]);
    }

    for (int kt = 0; kt < NT; ++kt) {
        const int cur = kt & 1;
        const int k0  = kt * 64;

        __syncthreads();

        if (kt + 1 < NT) {
            const int nk0 = (kt + 1) * 64;
            const int nb  = cur ^ 1;
#pragma unroll
            for (int u = 0; u < 2; ++u) {
                gl_lds16(kp + (size_t)nk0 * HD + kOff[u],
                         &lds[(nb ? AK1 : AK0) + kDst[u]]);
                gl_lds16(vp + nk0 + vOff[u],
                         &lds[(nb ? AV1 : AV0) + vDst[u]]);
            }
        }

        const short* kb = &lds[cur ? AK1 : AK0];
        const short* vb = &lds[cur ? AV1 : AV0];

        float mk[4];
#pragma unroll
        for (int c2 = 0; c2 < 4; ++c2) mk[c2] = mrow[k0 + 16 * c2 + m];

        f32x4 S[4];
        __builtin_amdgcn_s_setprio(1);
#pragma unroll
        for (int c2 = 0; c2 < 4; ++c2) {
            f32x4 acc = (f32x4){0.f, 0.f, 0.f, 0.f};
#pragma unroll
            for (int c = 0; c < 4; ++c) {
                int pk = (4 * c + quad) ^ sw;
                bf16x8 kf = *(const bf16x8*)&kb[(16 * c2 + m) * 128 + pk * 8];
                acc = __builtin_amdgcn_mfma_f32_16x16x32_bf16(qh[c], kf, acc, 0, 0, 0);
            }
            S[c2] = acc;
        }
        __builtin_amdgcn_s_setprio(0);

        // ---- online softmax: per-lane max only; shfl-reduce deferred ----
        float rloc[4];
#pragma unroll
        for (int r = 0; r < 4; ++r) {
            float s0 = S[0][r] + mk[0];
            float s1 = S[1][r] + mk[1];
            float s2 = S[2][r] + mk[2];
            float s3 = S[3][r] + mk[3];
            S[0][r] = s0; S[1][r] = s1; S[2][r] = s2; S[3][r] = s3;
            rloc[r] = fmaxf(fmaxf(s0, s1), fmaxf(s2, s3));
        }
        int needI = (rloc[0] > m_i[0] + 8.f) | (rloc[1] > m_i[1] + 8.f) |
                    (rloc[2] > m_i[2] + 8.f) | (rloc[3] > m_i[3] + 8.f);
        if (__any(needI)) {              // wave-uniform; rare after warmup
#pragma unroll
            for (int r = 0; r < 4; ++r) {
                float rm = rloc[r];
#pragma unroll
                for (int off = 1; off < 16; off <<= 1)
                    rm = fmaxf(rm, __shfl_xor(rm, off, 64));
                float mn = fmaxf(m_i[r], rm);
                float a  = __expf(m_i[r] - mn);
                m_i[r]   = mn;
                l_p[r]  *= a;
#pragma unroll
                for (int c = 0; c < 8; ++c) O[c][r] *= a;
            }
        }
        float p[4][4];
#pragma unroll
        for (int r = 0; r < 4; ++r) {
#pragma unroll
            for (int c2 = 0; c2 < 4; ++c2) p[c2][r] = __expf(S[c2][r] - m_i[r]);
            l_p[r] += (p[0][r] + p[1][r]) + (p[2][r] + p[3][r]);
        }

#pragma unroll
        for (int c2 = 0; c2 < 4; ++c2) {
#pragma unroll
            for (int jj = 0; jj < 2; ++jj) {
                unsigned pkw;
                asm("v_cvt_pk_bf16_f32 %0, %1, %2"
                    : "=v"(pkw) : "v"(p[c2][2 * jj]), "v"(p[c2][2 * jj + 1]));
                int ql = 4 * quad + 2 * jj;
                int qh2 = ql + 1;
                lds[pb + ql * 64 + (((2 * c2 + kcb) ^ (ql & 7)) << 3) + ml] =
                    (short)(pkw & 0xffffu);
                lds[pb + qh2 * 64 + (((2 * c2 + kcb) ^ (qh2 & 7)) << 3) + ml] =
                    (short)(pkw >> 16);
            }
        }

        __builtin_amdgcn_s_setprio(1);
#pragma unroll
        for (int cc = 0; cc < 2; ++cc) {
            int pv = (4 * cc + quad) ^ sw;
            bf16x8 pf = *(const bf16x8*)&lds[pb + m * 64 + (pv << 3)];
#pragma unroll
            for (int c = 0; c < 8; ++c) {
                bf16x8 vf = *(const bf16x8*)&vb[(16 * c + m) * 64 + pv * 8];
                O[c] = __builtin_amdgcn_mfma_f32_16x16x32_bf16(pf, vf, O[c], 0, 0, 0);
            }
        }
        __builtin_amdgcn_s_setprio(0);
    }

#pragma unroll
    for (int r = 0; r < 4; ++r) {
        float lv = l_p[r];
#pragma unroll
        for (int off = 1; off < 16; off <<= 1) lv += __shfl_xor(lv, off, 64);
        float inv = 1.0f / lv;
        int s = q0 + w * 16 + 4 * quad + r;
        size_t off2 = ((size_t)(b * SEQ + s)) * HID + h * HD;
#pragma unroll
        for (int c = 0; c < 8; ++c)
            ctxb[off2 + 16 * c + m] = f2bf(O[c][r] * inv);
    }
}

// ---------------------------------------------------------------------------
extern "C" void kernel_launch(void* const* d_in, const int* in_sizes, int n_in,
                              void* d_out, int out_size, void* d_ws, size_t ws_size,
                              hipStream_t stream) {
    const float* hs   = (const float*)d_in[0];
    const float* mask = (const float*)d_in[1];
    const float* Wqkv = (const float*)d_in[2];
    const float* bqkv = (const float*)d_in[3];
    const float* Wout = (const float*)d_in[4];
    const float* bout = (const float*)d_in[5];
    float* out = (float*)d_out;

    const size_t qkv_elems = (size_t)NBATCH * NH * SEQ * HD;  // 8.39M
    char* p = (char*)d_ws;
    float2* cst  = (float2*)p; p += (size_t)SEQ * HD * 8;   // fused cos/sin, 2 MB
    short* qbf   = (short*)p; p += qkv_elems * 2;
    short* kbf   = (short*)p; p += qkv_elems * 2;
    short* vTt   = (short*)p; p += qkv_elems * 2;
    short* Wqkvh = (short*)p; p += (size_t)3 * HID * HID * 2;
    short* Wouth = (short*)p; p += (size_t)HID * HID * 2;
    short* Ahs   = (short*)p; p += qkv_elems * 2;   // bf16(hs); aliased ctx after QKV
    short* ctxb  = Ahs;

    // fused prep: RoPE table + bf16 casts of hs / Wqkv / Wout (1 launch)
    prep_kernel<<<2048, 256, 0, stream>>>(hs, Wqkv, Wout, cst, Ahs, Wqkvh, Wouth);

    // QKV: M=4096, N=6144, K=2048 -> 384 blocks of 512 (8-phase 256^2, BK=64)
    gemm256_qkv_kernel<<<384, 512, 0, stream>>>(
        Ahs, Wqkvh, bqkv, qbf, kbf, vTt, cst);

    // attention: 512 XCD-swizzled blocks of 512 threads
    attn_mfma_kernel<<<512, 512, 0, stream>>>(qbf, kbf, vTt, mask, ctxb);

    // out-proj: M=4096, N=2048, K=2048 (m97 structure)
    gemm_out_kernel<<<dim3(16, 32), 256, 0, stream>>>(ctxb, Wouth, bout, out);
}

// Round 12
// 390.048 us; speedup vs baseline: 3.3062x; 1.0037x over previous
//
#include <hip/hip_runtime.h>
#include <math.h>

#define HID    2048
#define NH     16
#define HD     128
#define SEQ    2048
#define NBATCH 2
#define NT     (SEQ / 64)

typedef __attribute__((ext_vector_type(8))) short bf16x8;   // 8 bf16 = 4 VGPRs
typedef __attribute__((ext_vector_type(4))) float f32x4;    // MFMA accumulator

__device__ __forceinline__ short f2bf(float f) {            // fp32 -> bf16 RNE
    union { float f; unsigned u; } x; x.f = f;
    unsigned r = x.u + 0x7fffu + ((x.u >> 16) & 1u);
    return (short)(r >> 16);
}

// async global->LDS, 16 B per lane; LDS dest = wave-uniform base + lane*16
__device__ __forceinline__ void gl_lds16(const short* g, short* l) {
    __builtin_amdgcn_global_load_lds(
        (const __attribute__((address_space(1))) unsigned int*)g,
        (__attribute__((address_space(3))) unsigned int*)l, 16, 0, 0);
}

// ---------------------------------------------------------------------------
// Fused prep kernel: RoPE table + 3x fp32->bf16 casts in ONE launch.
// ---------------------------------------------------------------------------
#define ROPE_N  (SEQ * 64)                       // 131072
#define HS_N4   (NBATCH * SEQ * HID / 4)         // 2097152
#define WQKV_N4 (3 * HID * HID / 4)              // 3145728
#define WOUT_N4 (HID * HID / 4)                  // 1048576

__global__ __launch_bounds__(256) void prep_kernel(
    const float* __restrict__ hs, const float* __restrict__ Wqkv,
    const float* __restrict__ Wout,
    float2* __restrict__ cst, short* __restrict__ Ahs,
    short* __restrict__ Wqkvh, short* __restrict__ Wouth) {
    const long total = (long)ROPE_N + HS_N4 + WQKV_N4 + WOUT_N4;
    for (long idx = (long)blockIdx.x * 256 + threadIdx.x; idx < total;
         idx += (long)gridDim.x * 256) {
        if (idx < ROPE_N) {
            int s = (int)(idx >> 6);
            int i = (int)(idx & 63);
            double inv = pow(10000.0, -(double)i / 64.0);
            float freq = (float)s * (float)inv;
            float2 cs = make_float2(cosf(freq), sinf(freq));
            cst[s * HD + 2 * i]     = cs;
            cst[s * HD + 2 * i + 1] = cs;
        } else if (idx < (long)ROPE_N + HS_N4) {
            long i = idx - ROPE_N;
            float4 v = ((const float4*)hs)[i];
            short4 h;
            h.x = f2bf(v.x); h.y = f2bf(v.y); h.z = f2bf(v.z); h.w = f2bf(v.w);
            *(short4*)(Ahs + 4 * i) = h;
        } else if (idx < (long)ROPE_N + HS_N4 + WQKV_N4) {
            long i = idx - ROPE_N - HS_N4;
            float4 v = ((const float4*)Wqkv)[i];
            short4 h;
            h.x = f2bf(v.x); h.y = f2bf(v.y); h.z = f2bf(v.z); h.w = f2bf(v.w);
            *(short4*)(Wqkvh + 4 * i) = h;
        } else {
            long i = idx - ROPE_N - HS_N4 - WQKV_N4;
            float4 v = ((const float4*)Wout)[i];
            short4 h;
            h.x = f2bf(v.x); h.y = f2bf(v.y); h.z = f2bf(v.z); h.w = f2bf(v.w);
            *(short4*)(Wouth + 4 * i) = h;
        }
    }
}

// ---------------------------------------------------------------------------
// out-proj GEMM: m97 geometry, now with T3 minimum 2-phase double-buffer
// (same transformation that won attn round 1): prologue stage; per K-step
// ONE __syncthreads (its vmcnt(0) drain retires the prefetch issued a full
// compute phase earlier), then stage next buffer, then compute current.
// LDS 16 -> 32 KB (2 bufs); 3 blocks/CU by launch bounds (5 by LDS).
// MFMA order unchanged -> bit-identical output.
// ---------------------------------------------------------------------------
__global__ __launch_bounds__(256, 3) void gemm_out_kernel(
    const short* __restrict__ Ah, const short* __restrict__ Bh,
    const float* __restrict__ bias, float* __restrict__ C) {
    __shared__ short lds[16384];   // 2 bufs x {A 4096 | B 4096} shorts

    const int t     = threadIdx.x;
    const int w     = t >> 6;
    const int lane  = t & 63;
    const int mfrag = lane & 15;
    const int quad  = lane >> 4;
    const int wm    = (w >> 1) * 64;
    const int wn    = (w & 1) * 64;
    const int m0    = blockIdx.y * 128;
    const int n0    = blockIdx.x * 128;

    const int srow   = lane >> 2;
    const int schunk = (((lane & 3) ^ ((lane >> 3) & 3))) * 8;
    const short* gA0 = Ah + (size_t)(m0 + w * 16 + srow) * HID + schunk;
    const short* gA1 = Ah + (size_t)(m0 + 64 + w * 16 + srow) * HID + schunk;
    const short* gB0 = Bh + (size_t)(n0 + w * 16 + srow) * HID + schunk;
    const short* gB1 = Bh + (size_t)(n0 + 64 + w * 16 + srow) * HID + schunk;
    const int oA0 = (w * 16) * 32;
    const int oA1 = (64 + w * 16) * 32;
    const int oB0 = 4096 + (w * 16) * 32;
    const int oB1 = 4096 + (64 + w * 16) * 32;

    const int chA = 8 * (quad ^ ((mfrag >> 1) & 3));  // inverse swizzle

    f32x4 acc[4][4];
#pragma unroll
    for (int i = 0; i < 4; ++i)
#pragma unroll
        for (int j = 0; j < 4; ++j) acc[i][j] = (f32x4){0.f, 0.f, 0.f, 0.f};

    // prologue: stage K-step 0 into buf 0
    gl_lds16(gA0, &lds[oA0]);
    gl_lds16(gA1, &lds[oA1]);
    gl_lds16(gB0, &lds[oB0]);
    gl_lds16(gB1, &lds[oB1]);

    for (int kt = 0; kt < HID; kt += 32) {
        const int cur = (kt >> 5) & 1;

        // drains the prefetch issued last iteration (vmcnt0 in barrier) and
        // guarantees all waves done reading the buffer we stage into next
        __syncthreads();

        if (kt + 32 < HID) {
            const int nb = (cur ^ 1) * 8192;
            gl_lds16(gA0 + kt + 32, &lds[nb + oA0]);
            gl_lds16(gA1 + kt + 32, &lds[nb + oA1]);
            gl_lds16(gB0 + kt + 32, &lds[nb + oB0]);
            gl_lds16(gB1 + kt + 32, &lds[nb + oB1]);
        }

        const int cb = cur * 8192;
        bf16x8 ah[4], bh[4];
#pragma unroll
        for (int mt = 0; mt < 4; ++mt)
            ah[mt] = *(const bf16x8*)&lds[cb + (wm + mt * 16 + mfrag) * 32 + chA];
#pragma unroll
        for (int nt = 0; nt < 4; ++nt)
            bh[nt] = *(const bf16x8*)&lds[cb + 4096 + (wn + nt * 16 + mfrag) * 32 + chA];

#pragma unroll
        for (int mt = 0; mt < 4; ++mt)
#pragma unroll
            for (int nt = 0; nt < 4; ++nt)
                acc[mt][nt] = __builtin_amdgcn_mfma_f32_16x16x32_bf16(
                    ah[mt], bh[nt], acc[mt][nt], 0, 0, 0);
    }

    float bcol[4];
#pragma unroll
    for (int nt = 0; nt < 4; ++nt) bcol[nt] = bias[n0 + wn + nt * 16 + mfrag];

#pragma unroll
    for (int mt = 0; mt < 4; ++mt)
#pragma unroll
        for (int r = 0; r < 4; ++r) {
            int mm = m0 + wm + mt * 16 + 4 * quad + r;
#pragma unroll
            for (int nt = 0; nt < 4; ++nt)
                C[(size_t)mm * HID + n0 + wn + nt * 16 + mfrag] =
                    acc[mt][nt][r] + bcol[nt];
        }
}

// ---------------------------------------------------------------------------
// QKV GEMM: 256x256 tile, BK=64, 8-phase schedule (T2+T3+T4+T5 per m201).
// VERIFIED round-5 version (131 us, VGPR 128, MfmaUtil 33%). Register-bound
// to 1 block/CU (round-7 lesson: occupancy bound 4 -> acc spills, 8x slower).
// ---------------------------------------------------------------------------
#define PR1 __builtin_amdgcn_s_setprio(1)
#define PR0 __builtin_amdgcn_s_setprio(0)
#define BARX __builtin_amdgcn_s_barrier()
#define LGKM0 asm volatile("s_waitcnt lgkmcnt(0)" ::: "memory")
#define VMC(n) asm volatile("s_waitcnt vmcnt(" #n ")" ::: "memory")

#define STAGE_AH(bf, ke, hh) { _Pragma("unroll") for (int c = 0; c < 2; ++c) \
    gl_lds16(Ag + (size_t)(((hh) * 2 + c) * 64) * HID + (ke), \
             &lds[(bf) * 32768 + sdst + ((hh) * 2 + c) * 4096]); }
#define STAGE_BH(bf, ke, hh) { _Pragma("unroll") for (int c = 0; c < 2; ++c) \
    gl_lds16(Bg + (size_t)(((hh) * 2 + c) * 64) * HID + (ke), \
             &lds[(bf) * 32768 + 16384 + sdst + ((hh) * 2 + c) * 4096]); }

#define LOADA(bf, mh) { _Pragma("unroll") for (int x = 0; x < 4; ++x) { \
    aF[x][0] = *(const bf16x8*)&lds[(bf) * 32768 + aoff + ((mh) * 4 + x) * 1024 + fc0]; \
    aF[x][1] = *(const bf16x8*)&lds[(bf) * 32768 + aoff + ((mh) * 4 + x) * 1024 + fc1]; } }
#define LOADB(bf, nh, dstF) { _Pragma("unroll") for (int x = 0; x < 2; ++x) { \
    dstF[x][0] = *(const bf16x8*)&lds[(bf) * 32768 + 16384 + boff + ((nh) * 2 + x) * 1024 + fc0]; \
    dstF[x][1] = *(const bf16x8*)&lds[(bf) * 32768 + 16384 + boff + ((nh) * 2 + x) * 1024 + fc1]; } }
#define QUADM(mh, nh, bF) { _Pragma("unroll") for (int x = 0; x < 4; ++x) \
    _Pragma("unroll") for (int y = 0; y < 2; ++y) { \
    acc[(mh) * 4 + x][(nh) * 2 + y] = __builtin_amdgcn_mfma_f32_16x16x32_bf16( \
        aF[x][0], bF[y][0], acc[(mh) * 4 + x][(nh) * 2 + y], 0, 0, 0); \
    acc[(mh) * 4 + x][(nh) * 2 + y] = __builtin_amdgcn_mfma_f32_16x16x32_bf16( \
        aF[x][1], bF[y][1], acc[(mh) * 4 + x][(nh) * 2 + y], 0, 0, 0); } }

__global__ __launch_bounds__(512, 2) void gemm256_qkv_kernel(
    const short* __restrict__ Ah, const short* __restrict__ Bh,
    const float* __restrict__ bias,
    short* __restrict__ qb, short* __restrict__ kbf, short* __restrict__ vTt,
    const float2* __restrict__ cst) {
    __shared__ __align__(16) short lds[65536];   // 128 KB

    const int t    = threadIdx.x;
    const int w    = t >> 6;            // 0..7
    const int lane = t & 63;
    const int m    = lane & 15;
    const int quad = lane >> 4;
    const int wm   = w >> 2;            // 0..1  (M half)
    const int wn   = w & 3;             // 0..3  (N quarter)

    const int swz = (blockIdx.x & 7) * 48 + (blockIdx.x >> 3);
    const int bx  = swz / 16;           // 0..23 -> N
    const int by  = swz % 16;           // 0..15 -> M
    const int m0  = by * 256;
    const int n0  = bx * 256;

    const int srl = lane >> 3;
    const int sch = ((lane & 7) ^ (srl & 7)) * 8;
    const short* Ag = Ah + (size_t)(m0 + w * 8 + srl) * HID + sch;
    const short* Bg = Bh + (size_t)(n0 + w * 8 + srl) * HID + sch;
    const int sdst  = w * 512;          // wave's 8-row stripe (shorts)

    const int key  = m & 7;
    const int fc0  = (quad ^ key) * 8;
    const int fc1  = ((4 + quad) ^ key) * 8;
    const int aoff = (wm * 128 + m) * 64;
    const int boff = (wn * 64 + m) * 64;

    f32x4 acc[8][4];
#pragma unroll
    for (int i = 0; i < 8; ++i)
#pragma unroll
        for (int j = 0; j < 4; ++j) acc[i][j] = (f32x4){0.f, 0.f, 0.f, 0.f};

    bf16x8 aF[4][2], b0F[2][2], b1F[2][2];

    STAGE_AH(0, 0, 0); STAGE_AH(0, 0, 1);
    STAGE_BH(0, 0, 0); STAGE_BH(0, 0, 1);
    STAGE_BH(1, 64, 0); STAGE_BH(1, 64, 1);
    VMC(4); BARX;

    const int NIT = HID / 128;          // 16 iterations, 2 K-tiles each
#pragma unroll 1
    for (int i = 0; i < NIT; ++i) {
        const int k1   = i * 128 + 64;
        const int k2   = (i + 1) * 128;
        const int k3   = k2 + 64;
        const bool more = (i + 1 < NIT);
        LOADA(0, 0); LOADB(0, 0, b0F);
        STAGE_AH(1, k1, 0);
        BARX; LGKM0; PR1; QUADM(0, 0, b0F); PR0; BARX;
        LOADB(0, 1, b1F);
        STAGE_AH(1, k1, 1);
        BARX; LGKM0; PR1; QUADM(0, 1, b1F); PR0; BARX;
        LOADA(0, 1);
        if (more) STAGE_BH(0, k2, 0);
        BARX; LGKM0; PR1; QUADM(1, 1, b1F); PR0; BARX;
        if (more) { STAGE_BH(0, k2, 1); VMC(4); } else { VMC(0); }
        BARX; PR1; QUADM(1, 0, b0F); PR0; BARX;
        LOADA(1, 0); LOADB(1, 0, b0F);
        if (more) STAGE_AH(0, k2, 0);
        BARX; LGKM0; PR1; QUADM(0, 0, b0F); PR0; BARX;
        LOADB(1, 1, b1F);
        if (more) STAGE_AH(0, k2, 1);
        BARX; LGKM0; PR1; QUADM(0, 1, b1F); PR0; BARX;
        LOADA(1, 1);
        if (more) STAGE_BH(1, k3, 0);
        BARX; LGKM0; PR1; QUADM(1, 1, b1F); PR0; BARX;
        if (more) { STAGE_BH(1, k3, 1); VMC(4); }
        BARX; PR1; QUADM(1, 0, b0F); PR0; BARX;
    }

    const int which = n0 >> 11;          // 0=q 1=k 2=v
    const int bidx  = m0 >> 11;
    const int cb    = (n0 & 2047) + wn * 64;
    const int h     = cb >> 7;
    const int d0    = cb & 127;

    float bcol[4];
#pragma unroll
    for (int nt = 0; nt < 4; ++nt) bcol[nt] = bias[n0 + wn * 64 + nt * 16 + m];

    if (which < 2) {
        short* dst = (which == 0) ? qb : kbf;
        const float post = (which == 0) ? 0.08838834764831845f : 1.0f;
#pragma unroll
        for (int mt = 0; mt < 8; ++mt)
#pragma unroll
            for (int r = 0; r < 4; ++r) {
                int sl = (m0 & 2047) + wm * 128 + mt * 16 + 4 * quad + r;
                const float2* csr = cst + (size_t)sl * HD;
                size_t rowb = ((size_t)(bidx * NH + h) * SEQ + sl) * HD;
#pragma unroll
                for (int nt = 0; nt < 4; ++nt) {
                    float x  = acc[mt][nt][r] + bcol[nt];
                    float px = __shfl_xor(x, 1, 64);   // RoPE pair partner
                    int   d  = d0 + nt * 16 + m;
                    float2 cs = csr[d];
                    float rot = (m & 1) ? fmaf(px, cs.y, x * cs.x)
                                        : (x * cs.x - px * cs.y);
                    dst[rowb + d] = f2bf(rot * post);
                }
            }
    } else {
        short* tw = &lds[w * 8192];      // 64 d-rows x 128 s, chunk ^= d&15
#pragma unroll
        for (int mt = 0; mt < 8; ++mt)
#pragma unroll
            for (int nt = 0; nt < 4; ++nt)
#pragma unroll
                for (int r = 0; r < 4; ++r) {
                    int s_l = mt * 16 + 4 * quad + r;
                    int d_l = nt * 16 + m;
                    tw[d_l * 128 + (((s_l >> 3) ^ m) << 3) + (s_l & 7)] =
                        f2bf(acc[mt][nt][r] + bcol[nt]);
                }
        const size_t vbase = (size_t)(bidx * NH + h) * HD * SEQ;
        const int sbase = (m0 & 2047) + wm * 128;
#pragma unroll
        for (int it = 0; it < 16; ++it) {
            int d_l = it * 4 + quad;
            bf16x8 row = *(const bf16x8*)&tw[d_l * 128 + ((m ^ (d_l & 15)) << 3)];
            *(bf16x8*)(vTt + vbase + (size_t)(d0 + d_l) * SEQ + sbase + m * 8) = row;
        }
    }
}

// ---------------------------------------------------------------------------
// MFMA flash attention (verified; round-11 deferred shfl-reduce): 8 waves,
// q-tile 128, KV tile 64 double-buffered, defer-max softmax, cvt_pk, setprio.
// ---------------------------------------------------------------------------
#define AK0 0
#define AK1 8192
#define AV0 16384
#define AV1 24576
#define AP  32768

__global__ __launch_bounds__(512, 4) void attn_mfma_kernel(
    const short* __restrict__ qb, const short* __restrict__ kbf,
    const short* __restrict__ vTt, const float* __restrict__ mask,
    short* __restrict__ ctxb) {
    __shared__ __align__(16) short lds[40960];   // 80 KB

    const int t    = threadIdx.x;
    const int w    = t >> 6;            // 0..7
    const int lane = t & 63;
    const int m    = lane & 15;
    const int quad = lane >> 4;

    const int id  = blockIdx.x;
    const int j   = id >> 3;
    const int bh  = (id & 7) * 4 + (j >> 4);
    const int q0  = (j & 15) * 128;
    const int b   = bh >> 4;
    const int h   = bh & 15;

    const size_t base = (size_t)bh * SEQ * HD;
    const short* kp = kbf + base;        // [s][d]
    const short* vp = vTt + base;        // [d][s]
    const float* mrow = mask + (size_t)b * SEQ;

    size_t kOff[2], vOff[2];
    int kDst[2], vDst[2];
#pragma unroll
    for (int u = 0; u < 2; ++u) {
        int rk = w * 8 + u * 4 + (lane >> 4);
        int ck = (lane & 15) ^ (rk & 7);
        kOff[u] = (size_t)rk * HD + ck * 8;
        kDst[u] = (w * 8 + u * 4) * 128;
        int rv = w * 16 + u * 8 + (lane >> 3);
        int cv = (lane & 7) ^ (rv & 7);
        vOff[u] = (size_t)rv * SEQ + cv * 8;
        vDst[u] = (w * 16 + u * 8) * 64;
    }

    const int srow = q0 + w * 16 + m;
    bf16x8 qh[4];
    {
        const short* qhp = qb + base + (size_t)srow * HD;
#pragma unroll
        for (int c = 0; c < 4; ++c)
            qh[c] = *(const bf16x8*)(qhp + 32 * c + 8 * quad);
    }

    f32x4 O[8];
    float m_i[4], l_p[4];
#pragma unroll
    for (int c = 0; c < 8; ++c) O[c] = (f32x4){0.f, 0.f, 0.f, 0.f};
#pragma unroll
    for (int r = 0; r < 4; ++r) { m_i[r] = -INFINITY; l_p[r] = 0.f; }

    const int sw = m & 7;
    const int pb = AP + w * 1024;
    const int kcb = (m >> 3);
    const int ml  = m & 7;

#pragma unroll
    for (int u = 0; u < 2; ++u) {
        gl_lds16(kp + kOff[u], &lds[AK0 + kDst[u]]);
        gl_lds16(vp + vOff[u], &lds[AV0 + vDst[u]]);
    }

    for (int kt = 0; kt < NT; ++kt) {
        const int cur = kt & 1;
        const int k0  = kt * 64;

        __syncthreads();

        if (kt + 1 < NT) {
            const int nk0 = (kt + 1) * 64;
            const int nb  = cur ^ 1;
#pragma unroll
            for (int u = 0; u < 2; ++u) {
                gl_lds16(kp + (size_t)nk0 * HD + kOff[u],
                         &lds[(nb ? AK1 : AK0) + kDst[u]]);
                gl_lds16(vp + nk0 + vOff[u],
                         &lds[(nb ? AV1 : AV0) + vDst[u]]);
            }
        }

        const short* kb = &lds[cur ? AK1 : AK0];
        const short* vb = &lds[cur ? AV1 : AV0];

        float mk[4];
#pragma unroll
        for (int c2 = 0; c2 < 4; ++c2) mk[c2] = mrow[k0 + 16 * c2 + m];

        f32x4 S[4];
        __builtin_amdgcn_s_setprio(1);
#pragma unroll
        for (int c2 = 0; c2 < 4; ++c2) {
            f32x4 acc = (f32x4){0.f, 0.f, 0.f, 0.f};
#pragma unroll
            for (int c = 0; c < 4; ++c) {
                int pk = (4 * c + quad) ^ sw;
                bf16x8 kf = *(const bf16x8*)&kb[(16 * c2 + m) * 128 + pk * 8];
                acc = __builtin_amdgcn_mfma_f32_16x16x32_bf16(qh[c], kf, acc, 0, 0, 0);
            }
            S[c2] = acc;
        }
        __builtin_amdgcn_s_setprio(0);

        // ---- online softmax: per-lane max only; shfl-reduce deferred ----
        float rloc[4];
#pragma unroll
        for (int r = 0; r < 4; ++r) {
            float s0 = S[0][r] + mk[0];
            float s1 = S[1][r] + mk[1];
            float s2 = S[2][r] + mk[2];
            float s3 = S[3][r] + mk[3];
            S[0][r] = s0; S[1][r] = s1; S[2][r] = s2; S[3][r] = s3;
            rloc[r] = fmaxf(fmaxf(s0, s1), fmaxf(s2, s3));
        }
        int needI = (rloc[0] > m_i[0] + 8.f) | (rloc[1] > m_i[1] + 8.f) |
                    (rloc[2] > m_i[2] + 8.f) | (rloc[3] > m_i[3] + 8.f);
        if (__any(needI)) {              // wave-uniform; rare after warmup
#pragma unroll
            for (int r = 0; r < 4; ++r) {
                float rm = rloc[r];
#pragma unroll
                for (int off = 1; off < 16; off <<= 1)
                    rm = fmaxf(rm, __shfl_xor(rm, off, 64));
                float mn = fmaxf(m_i[r], rm);
                float a  = __expf(m_i[r] - mn);
                m_i[r]   = mn;
                l_p[r]  *= a;
#pragma unroll
                for (int c = 0; c < 8; ++c) O[c][r] *= a;
            }
        }
        float p[4][4];
#pragma unroll
        for (int r = 0; r < 4; ++r) {
#pragma unroll
            for (int c2 = 0; c2 < 4; ++c2) p[c2][r] = __expf(S[c2][r] - m_i[r]);
            l_p[r] += (p[0][r] + p[1][r]) + (p[2][r] + p[3][r]);
        }

#pragma unroll
        for (int c2 = 0; c2 < 4; ++c2) {
#pragma unroll
            for (int jj = 0; jj < 2; ++jj) {
                unsigned pkw;
                asm("v_cvt_pk_bf16_f32 %0, %1, %2"
                    : "=v"(pkw) : "v"(p[c2][2 * jj]), "v"(p[c2][2 * jj + 1]));
                int ql = 4 * quad + 2 * jj;
                int qh2 = ql + 1;
                lds[pb + ql * 64 + (((2 * c2 + kcb) ^ (ql & 7)) << 3) + ml] =
                    (short)(pkw & 0xffffu);
                lds[pb + qh2 * 64 + (((2 * c2 + kcb) ^ (qh2 & 7)) << 3) + ml] =
                    (short)(pkw >> 16);
            }
        }

        __builtin_amdgcn_s_setprio(1);
#pragma unroll
        for (int cc = 0; cc < 2; ++cc) {
            int pv = (4 * cc + quad) ^ sw;
            bf16x8 pf = *(const bf16x8*)&lds[pb + m * 64 + (pv << 3)];
#pragma unroll
            for (int c = 0; c < 8; ++c) {
                bf16x8 vf = *(const bf16x8*)&vb[(16 * c + m) * 64 + pv * 8];
                O[c] = __builtin_amdgcn_mfma_f32_16x16x32_bf16(pf, vf, O[c], 0, 0, 0);
            }
        }
        __builtin_amdgcn_s_setprio(0);
    }

#pragma unroll
    for (int r = 0; r < 4; ++r) {
        float lv = l_p[r];
#pragma unroll
        for (int off = 1; off < 16; off <<= 1) lv += __shfl_xor(lv, off, 64);
        float inv = 1.0f / lv;
        int s = q0 + w * 16 + 4 * quad + r;
        size_t off2 = ((size_t)(b * SEQ + s)) * HID + h * HD;
#pragma unroll
        for (int c = 0; c < 8; ++c)
            ctxb[off2 + 16 * c + m] = f2bf(O[c][r] * inv);
    }
}

// ---------------------------------------------------------------------------
extern "C" void kernel_launch(void* const* d_in, const int* in_sizes, int n_in,
                              void* d_out, int out_size, void* d_ws, size_t ws_size,
                              hipStream_t stream) {
    const float* hs   = (const float*)d_in[0];
    const float* mask = (const float*)d_in[1];
    const float* Wqkv = (const float*)d_in[2];
    const float* bqkv = (const float*)d_in[3];
    const float* Wout = (const float*)d_in[4];
    const float* bout = (const float*)d_in[5];
    float* out = (float*)d_out;

    const size_t qkv_elems = (size_t)NBATCH * NH * SEQ * HD;  // 8.39M
    char* p = (char*)d_ws;
    float2* cst  = (float2*)p; p += (size_t)SEQ * HD * 8;   // fused cos/sin, 2 MB
    short* qbf   = (short*)p; p += qkv_elems * 2;
    short* kbf   = (short*)p; p += qkv_elems * 2;
    short* vTt   = (short*)p; p += qkv_elems * 2;
    short* Wqkvh = (short*)p; p += (size_t)3 * HID * HID * 2;
    short* Wouth = (short*)p; p += (size_t)HID * HID * 2;
    short* Ahs   = (short*)p; p += qkv_elems * 2;   // bf16(hs); aliased ctx after QKV
    short* ctxb  = Ahs;

    // fused prep: RoPE table + bf16 casts of hs / Wqkv / Wout (1 launch)
    prep_kernel<<<2048, 256, 0, stream>>>(hs, Wqkv, Wout, cst, Ahs, Wqkvh, Wouth);

    // QKV: M=4096, N=6144, K=2048 -> 384 blocks of 512 (8-phase 256^2, BK=64)
    gemm256_qkv_kernel<<<384, 512, 0, stream>>>(
        Ahs, Wqkvh, bqkv, qbf, kbf, vTt, cst);

    // attention: 512 XCD-swizzled blocks of 512 threads
    attn_mfma_kernel<<<512, 512, 0, stream>>>(qbf, kbf, vTt, mask, ctxb);

    // out-proj: M=4096, N=2048, K=2048 (m97 geometry + 2-phase dbuf)
    gemm_out_kernel<<<dim3(16, 32), 256, 0, stream>>>(ctxb, Wouth, bout, out);
}